// Round 1
// baseline (800.551 us; speedup 1.0000x reference)
//
#include <hip/hip_runtime.h>

// ---------------------------------------------------------------------------
// MultiheadSelfAttention: x[4,2048,1024] fp32, Wq/Wk/Wv/Wo [1024,1024] fp32
// out = MHSA(x) @ ... -> [4,2048,1024] fp32
//
// Strategy: hi/lo bf16 split (3-MFMA fp32 emulation) for ALL matmuls:
//   A*B ~= Ah*Bh + Ah*Bl + Al*Bh   (error ~2^-17 relative)
// Projections: tiled 128x128 MFMA GEMM. Attention: flash-style with swapped
// QK^T (mfma(K,Q)) so P stays lane-local; V stored transposed for cheap
// B-operand fragment reads.
// ---------------------------------------------------------------------------

#define DMODEL 1024
#define NH 16
#define DKH 64
#define NB 4
#define SEQ 2048
#define NT (NB*SEQ)   // 8192 tokens
#define NBH (NB*NH)   // 64 (batch*heads)

typedef __attribute__((ext_vector_type(8))) short bf16x8;   // 8 bf16 in 4 VGPR
typedef __attribute__((ext_vector_type(4))) float f32x4;

#define MFMA16(a, b, c) __builtin_amdgcn_mfma_f32_16x16x32_bf16((a), (b), (c), 0, 0, 0)

// ------------------------- device scratch (static) -------------------------
__device__ ushort g_xhi[NT*DMODEL],  g_xlo[NT*DMODEL];
__device__ ushort g_wqhi[DMODEL*DMODEL], g_wqlo[DMODEL*DMODEL];
__device__ ushort g_wkhi[DMODEL*DMODEL], g_wklo[DMODEL*DMODEL];
__device__ ushort g_wvhi[DMODEL*DMODEL], g_wvlo[DMODEL*DMODEL];
__device__ ushort g_wohi[DMODEL*DMODEL], g_wolo[DMODEL*DMODEL];
__device__ ushort g_qhi[NBH*SEQ*DKH],  g_qlo[NBH*SEQ*DKH];
__device__ ushort g_khi[NBH*SEQ*DKH],  g_klo[NBH*SEQ*DKH];
__device__ ushort g_vthi[NBH*DKH*SEQ], g_vtlo[NBH*DKH*SEQ];   // V transposed: [bh][d][s]
__device__ ushort g_aohi[NT*DMODEL],   g_aolo[NT*DMODEL];     // attention out, merged heads

// ------------------------- helpers -------------------------
static __device__ __forceinline__ ushort f2bf(float f) {
    unsigned u = __float_as_uint(f);
    unsigned r = (u + 0x7fffu + ((u >> 16) & 1u)) >> 16;   // RNE
    return (ushort)r;
}
static __device__ __forceinline__ float bf2f(ushort h) {
    return __uint_as_float(((unsigned)h) << 16);
}

// ------------------------- fp32 -> (hi,lo) bf16 convert -------------------------
template<int DST>
__global__ void cvt_hilo(const float* __restrict__ src, int n4) {
    ushort* hi; ushort* lo;
    if      (DST == 0) { hi = g_xhi;  lo = g_xlo;  }
    else if (DST == 1) { hi = g_wqhi; lo = g_wqlo; }
    else if (DST == 2) { hi = g_wkhi; lo = g_wklo; }
    else if (DST == 3) { hi = g_wvhi; lo = g_wvlo; }
    else               { hi = g_wohi; lo = g_wolo; }
    int stride = gridDim.x * blockDim.x;
    for (int i = blockIdx.x * blockDim.x + threadIdx.x; i < n4; i += stride) {
        float4 f = ((const float4*)src)[i];
        ushort4 h, l;
        h.x = f2bf(f.x); l.x = f2bf(f.x - bf2f(h.x));
        h.y = f2bf(f.y); l.y = f2bf(f.y - bf2f(h.y));
        h.z = f2bf(f.z); l.z = f2bf(f.z - bf2f(h.z));
        h.w = f2bf(f.w); l.w = f2bf(f.w - bf2f(h.w));
        ((ushort4*)hi)[i] = h;
        ((ushort4*)lo)[i] = l;
    }
}

// ------------------------- hi/lo GEMM: C[m][n] = sum_k A[m][k]*B[n][k] -------------------------
// WHICH: 0=Q proj, 1=K proj, 2=V proj (store transposed), 3=output proj (fp32 to d_out)
template<int WHICH>
__global__ __launch_bounds__(256) void gemm_hilo(float* __restrict__ outf) {
    __shared__ ushort sAh[128*32], sAl[128*32], sBh[128*32], sBl[128*32];

    const ushort* Ahi = (WHICH == 3) ? g_aohi : g_xhi;
    const ushort* Alo = (WHICH == 3) ? g_aolo : g_xlo;
    const ushort* Bhi = (WHICH == 0) ? g_wqhi : (WHICH == 1) ? g_wkhi : (WHICH == 2) ? g_wvhi : g_wohi;
    const ushort* Blo = (WHICH == 0) ? g_wqlo : (WHICH == 1) ? g_wklo : (WHICH == 2) ? g_wvlo : g_wolo;

    const int tid  = threadIdx.x;
    const int lane = tid & 63;
    const int wid  = tid >> 6;
    const int fr   = lane & 15;     // fragment row/col within 16
    const int fg   = lane >> 4;     // k-group
    const int n0 = blockIdx.x * 128;
    const int m0 = blockIdx.y * 128;
    const int wm = (wid >> 1) * 64; // wave's 64x64 quadrant
    const int wn = (wid & 1) * 64;

    f32x4 acc[4][4];
    const f32x4 zv = {0.f, 0.f, 0.f, 0.f};
#pragma unroll
    for (int i = 0; i < 4; ++i)
#pragma unroll
        for (int j = 0; j < 4; ++j) acc[i][j] = zv;

    for (int k0 = 0; k0 < DMODEL; k0 += 32) {
        __syncthreads();
#pragma unroll
        for (int i = 0; i < 2; ++i) {
            int ch  = tid + i * 256;          // 512 chunks of 16B per buffer
            int row = ch >> 2;
            int cc  = (ch & 3) << 3;          // element offset in row
            size_t ga = (size_t)(m0 + row) * DMODEL + k0 + cc;
            size_t gb = (size_t)(n0 + row) * DMODEL + k0 + cc;
            *(uint4*)&sAh[row*32 + cc] = *(const uint4*)(Ahi + ga);
            *(uint4*)&sAl[row*32 + cc] = *(const uint4*)(Alo + ga);
            *(uint4*)&sBh[row*32 + cc] = *(const uint4*)(Bhi + gb);
            *(uint4*)&sBl[row*32 + cc] = *(const uint4*)(Blo + gb);
        }
        __syncthreads();

        bf16x8 bh4[4], bl4[4];
#pragma unroll
        for (int nf = 0; nf < 4; ++nf) {
            int off = (wn + nf*16 + fr) * 32 + fg * 8;
            bh4[nf] = *(const bf16x8*)&sBh[off];
            bl4[nf] = *(const bf16x8*)&sBl[off];
        }
#pragma unroll
        for (int mf = 0; mf < 4; ++mf) {
            int off = (wm + mf*16 + fr) * 32 + fg * 8;
            bf16x8 ah = *(const bf16x8*)&sAh[off];
            bf16x8 al = *(const bf16x8*)&sAl[off];
#pragma unroll
            for (int nf = 0; nf < 4; ++nf) {
                acc[mf][nf] = MFMA16(ah, bh4[nf], acc[mf][nf]);
                acc[mf][nf] = MFMA16(ah, bl4[nf], acc[mf][nf]);
                acc[mf][nf] = MFMA16(al, bh4[nf], acc[mf][nf]);
            }
        }
    }

    // epilogue: C row = mf*16 + 4*fg + r, col = nf*16 + fr  (m89-verified C/D layout)
#pragma unroll
    for (int mf = 0; mf < 4; ++mf)
#pragma unroll
        for (int nf = 0; nf < 4; ++nf)
#pragma unroll
            for (int r = 0; r < 4; ++r) {
                float v = acc[mf][nf][r];
                int m = m0 + wm + mf*16 + fg*4 + r;   // token index
                int n = n0 + wn + nf*16 + fr;         // output channel
                if (WHICH == 3) {
                    outf[(size_t)m * DMODEL + n] = v;
                } else {
                    int b = m >> 11, s = m & (SEQ - 1);
                    int h = n >> 6,  d = n & 63;
                    ushort hv = f2bf(v);
                    ushort lv = f2bf(v - bf2f(hv));
                    if (WHICH == 2) {   // V transposed: [bh][d][s]
                        size_t idx = ((size_t)(b*NH + h) * DKH + d) * SEQ + s;
                        g_vthi[idx] = hv; g_vtlo[idx] = lv;
                    } else {
                        size_t idx = ((size_t)(b*NH + h) * SEQ + s) * DKH + d;
                        if (WHICH == 0) { g_qhi[idx] = hv; g_qlo[idx] = lv; }
                        else            { g_khi[idx] = hv; g_klo[idx] = lv; }
                    }
                }
            }
}

// ------------------------- flash attention (causal) -------------------------
// grid: (SEQ/64, NBH), 256 threads = 4 waves; wave w owns q rows [q0+16w, q0+16w+16)
// swapped QK^T: mfma(K, Q) -> lane holds q = lane&15, kv = 4*(lane>>4)+reg
__global__ __launch_bounds__(256) void attn_kernel() {
    __shared__ ushort sKh[32*64], sKl[32*64];   // [kv][d], rows XOR-swizzled by (kv&7)
    __shared__ ushort sVh[64*32], sVl[64*32];   // [d][kv], chunks XOR-swizzled by (d>>1)&3

    const int tid  = threadIdx.x;
    const int lane = tid & 63;
    const int wid  = tid >> 6;
    const int fr   = lane & 15;
    const int fg   = lane >> 4;
    const int qb   = blockIdx.x;
    const int bh   = blockIdx.y;
    const int q0   = qb * 64;
    const int qw   = q0 + wid * 16;          // wave's first q row
    const int qs   = qw + fr;                // this lane's softmax row
    const size_t qkb = (size_t)bh * SEQ * DKH;
    const size_t vtb = (size_t)bh * DKH * SEQ;
    const float SCL = 0.125f * 1.44269504088896341f;   // 1/sqrt(64) * log2(e)

    // Q fragments (B-operand): col q = fr, k(d) = fg*8 + i + 32*dh
    bf16x8 Qh[2], Ql[2];
#pragma unroll
    for (int dh = 0; dh < 2; ++dh) {
        size_t o = qkb + (size_t)(qw + fr) * DKH + fg * 8 + dh * 32;
        Qh[dh] = *(const bf16x8*)(g_qhi + o);
        Ql[dh] = *(const bf16x8*)(g_qlo + o);
    }

    float m_run = -1e30f, l_run = 0.f;
    f32x4 accO[4];
    const f32x4 zv = {0.f, 0.f, 0.f, 0.f};
#pragma unroll
    for (int i = 0; i < 4; ++i) accO[i] = zv;

    const int nt = (q0 + 64) / 32;
    for (int t = 0; t < nt; ++t) {
        const int kv0 = t * 32;
        __syncthreads();
        {   // stage K tile [32][64] (swizzled) and V^T tile [64][32] (swizzled)
            int row = tid >> 3, c = tid & 7;
            size_t gk = qkb + (size_t)(kv0 + row) * DKH + c * 8;
            int cs = c ^ (row & 7);
            *(uint4*)&sKh[row*64 + cs*8] = *(const uint4*)(g_khi + gk);
            *(uint4*)&sKl[row*64 + cs*8] = *(const uint4*)(g_klo + gk);
            int d = tid >> 2, cv = tid & 3;
            size_t gv = vtb + (size_t)d * SEQ + kv0 + cv * 8;
            int cvs = cv ^ ((d >> 1) & 3);
            *(uint4*)&sVh[d*32 + cvs*8] = *(const uint4*)(g_vthi + gv);
            *(uint4*)&sVl[d*32 + cvs*8] = *(const uint4*)(g_vtlo + gv);
        }
        __syncthreads();

        if (kv0 > qw + 15) continue;   // wave-uniform: tile fully masked for this wave

        // ---- scores: accS[kg] : D[kv][q], kv = kg*16 + 4*fg + r, q = fr
        f32x4 accS[2] = { zv, zv };
#pragma unroll
        for (int kg = 0; kg < 2; ++kg) {
#pragma unroll
            for (int dh = 0; dh < 2; ++dh) {
                int rowbyte = (kg*16 + fr) * 128;
                int off = ((fg*16 + dh*64) ^ ((fr & 7) << 4));
                bf16x8 kh = *(const bf16x8*)((const char*)sKh + rowbyte + off);
                bf16x8 kl = *(const bf16x8*)((const char*)sKl + rowbyte + off);
                accS[kg] = MFMA16(kh, Qh[dh], accS[kg]);
                accS[kg] = MFMA16(kh, Ql[dh], accS[kg]);
                accS[kg] = MFMA16(kl, Qh[dh], accS[kg]);
            }
        }

        // ---- online softmax (lane owns row qs; partner lanes at xor 16/32)
        float p[8];
        float mt = -1e30f;
#pragma unroll
        for (int kg = 0; kg < 2; ++kg)
#pragma unroll
            for (int r = 0; r < 4; ++r) {
                float s = accS[kg][r] * SCL;
                int kv = kv0 + kg*16 + fg*4 + r;
                if (kv > qs) s = -1e30f;
                p[kg*4 + r] = s;
                mt = fmaxf(mt, s);
            }
        mt = fmaxf(mt, __shfl_xor(mt, 16));
        mt = fmaxf(mt, __shfl_xor(mt, 32));
        float mn   = fmaxf(m_run, mt);
        float corr = exp2f(m_run - mn);
        float rs = 0.f;
#pragma unroll
        for (int i = 0; i < 8; ++i) { p[i] = exp2f(p[i] - mn); rs += p[i]; }
        rs += __shfl_xor(rs, 16);
        rs += __shfl_xor(rs, 32);
        l_run = l_run * corr + rs;
        m_run = mn;

        // ---- rescale O (O element r is q-row 4*fg+r; factor lives in lane (4*fg+r))
        float c4[4];
#pragma unroll
        for (int r = 0; r < 4; ++r) c4[r] = __shfl(corr, fg*4 + r);
#pragma unroll
        for (int ds = 0; ds < 4; ++ds)
#pragma unroll
            for (int r = 0; r < 4; ++r) accO[ds][r] *= c4[r];

        // ---- P -> bf16 hi/lo fragments (split-k map: elem i <-> kv = 16*(i>>2)+4*fg+(i&3))
        bf16x8 ph, pl;
#pragma unroll
        for (int i = 0; i < 8; ++i) {
            ushort h = f2bf(p[i]);
            ph[i] = (short)h;
            pl[i] = (short)f2bf(p[i] - bf2f(h));
        }

        // ---- PV: accO[ds] += P * V  (V fragment uses the same split-k map)
#pragma unroll
        for (int ds = 0; ds < 4; ++ds) {
            int d = ds*16 + fr;
            int rowbyte = d * 64;
            int key = (d & 6) << 3;
            int o1 = (fg*8)      ^ key;
            int o2 = (fg*8 + 32) ^ key;
            union { bf16x8 v; uint2 u[2]; } Vhh, Vll;
            Vhh.u[0] = *(const uint2*)((const char*)sVh + rowbyte + o1);
            Vhh.u[1] = *(const uint2*)((const char*)sVh + rowbyte + o2);
            Vll.u[0] = *(const uint2*)((const char*)sVl + rowbyte + o1);
            Vll.u[1] = *(const uint2*)((const char*)sVl + rowbyte + o2);
            accO[ds] = MFMA16(ph, Vhh.v, accO[ds]);
            accO[ds] = MFMA16(ph, Vll.v, accO[ds]);
            accO[ds] = MFMA16(pl, Vhh.v, accO[ds]);
        }
    }

    // ---- epilogue: normalize and store merged-head output as hi/lo bf16
    float l4[4];
#pragma unroll
    for (int r = 0; r < 4; ++r) l4[r] = __shfl(l_run, fg*4 + r);
#pragma unroll
    for (int ds = 0; ds < 4; ++ds)
#pragma unroll
        for (int r = 0; r < 4; ++r) {
            float v = accO[ds][r] / l4[r];
            int q   = qw + fg*4 + r;
            int tkn = (bh >> 4) * SEQ + q;
            int col = (bh & 15) * DKH + ds*16 + fr;
            size_t idx = (size_t)tkn * DMODEL + col;
            ushort hv = f2bf(v);
            g_aohi[idx] = hv;
            g_aolo[idx] = f2bf(v - bf2f(hv));
        }
}

// ------------------------- launcher -------------------------
extern "C" void kernel_launch(void* const* d_in, const int* in_sizes, int n_in,
                              void* d_out, int out_size, void* d_ws, size_t ws_size,
                              hipStream_t stream) {
    const float* x  = (const float*)d_in[0];
    const float* wq = (const float*)d_in[1];
    const float* wk = (const float*)d_in[2];
    const float* wv = (const float*)d_in[3];
    const float* wo = (const float*)d_in[4];
    float* out = (float*)d_out;

    cvt_hilo<0><<<2048, 256, 0, stream>>>(x,  (NT*DMODEL)/4);
    cvt_hilo<1><<<512,  256, 0, stream>>>(wq, (DMODEL*DMODEL)/4);
    cvt_hilo<2><<<512,  256, 0, stream>>>(wk, (DMODEL*DMODEL)/4);
    cvt_hilo<3><<<512,  256, 0, stream>>>(wv, (DMODEL*DMODEL)/4);
    cvt_hilo<4><<<512,  256, 0, stream>>>(wo, (DMODEL*DMODEL)/4);

    dim3 gg(DMODEL/128, NT/128);
    gemm_hilo<0><<<gg, 256, 0, stream>>>(out);
    gemm_hilo<1><<<gg, 256, 0, stream>>>(out);
    gemm_hilo<2><<<gg, 256, 0, stream>>>(out);

    attn_kernel<<<dim3(SEQ/64, NBH), 256, 0, stream>>>();

    gemm_hilo<3><<<gg, 256, 0, stream>>>(out);
}

// Round 4
// 691.191 us; speedup vs baseline: 1.1582x; 1.1582x over previous
//
#include <hip/hip_runtime.h>

// ---------------------------------------------------------------------------
// MultiheadSelfAttention fp32 via hi/lo bf16 split (3-MFMA emulation).
// R4 = R3 resubmit (two infra timeouts; never benched):
//  - global_load_lds staging everywhere (pre-swizzled global source)
//  - GEMM fragment reads: chunk = fg ^ ((row>>1)&3)  (8-way -> 2-way banks)
//  - attention: KV-tile 64, causal sub-tile guards, Q pre-scaled
// ---------------------------------------------------------------------------

#define DMODEL 1024
#define NH 16
#define DKH 64
#define NB 4
#define SEQ 2048
#define NT (NB*SEQ)   // 8192 tokens
#define NBH (NB*NH)   // 64

typedef __attribute__((ext_vector_type(8))) short bf16x8;
typedef __attribute__((ext_vector_type(4))) float f32x4;
typedef unsigned int u32;

#define MFMA16(a, b, c) __builtin_amdgcn_mfma_f32_16x16x32_bf16((a), (b), (c), 0, 0, 0)
#define GLDS16(gp, lp) \
    __builtin_amdgcn_global_load_lds((const __attribute__((address_space(1))) u32*)(const void*)(gp), \
                                     (__attribute__((address_space(3))) u32*)(void*)(lp), 16, 0, 0)

// ------------------------- device scratch -------------------------
__device__ ushort g_xhi[NT*DMODEL],  g_xlo[NT*DMODEL];
__device__ ushort g_wqhi[DMODEL*DMODEL], g_wqlo[DMODEL*DMODEL];
__device__ ushort g_wkhi[DMODEL*DMODEL], g_wklo[DMODEL*DMODEL];
__device__ ushort g_wvhi[DMODEL*DMODEL], g_wvlo[DMODEL*DMODEL];
__device__ ushort g_wohi[DMODEL*DMODEL], g_wolo[DMODEL*DMODEL];
__device__ ushort g_qhi[NBH*SEQ*DKH],  g_qlo[NBH*SEQ*DKH];    // pre-scaled by 1/8*log2e
__device__ ushort g_khi[NBH*SEQ*DKH],  g_klo[NBH*SEQ*DKH];
__device__ ushort g_vthi[NBH*DKH*SEQ], g_vtlo[NBH*DKH*SEQ];   // V^T: [bh][d][s]
__device__ ushort g_aohi[NT*DMODEL],   g_aolo[NT*DMODEL];

// ------------------------- helpers -------------------------
static __device__ __forceinline__ ushort f2bf(float f) {
    unsigned u = __float_as_uint(f);
    return (ushort)((u + 0x7fffu + ((u >> 16) & 1u)) >> 16);
}
static __device__ __forceinline__ float bf2f(ushort h) {
    return __uint_as_float(((unsigned)h) << 16);
}

// ------------------------- fp32 -> (hi,lo) bf16 -------------------------
template<int DST>
__global__ void cvt_hilo(const float* __restrict__ src, int n4) {
    ushort* hi; ushort* lo;
    if      (DST == 0) { hi = g_xhi;  lo = g_xlo;  }
    else if (DST == 1) { hi = g_wqhi; lo = g_wqlo; }
    else if (DST == 2) { hi = g_wkhi; lo = g_wklo; }
    else if (DST == 3) { hi = g_wvhi; lo = g_wvlo; }
    else               { hi = g_wohi; lo = g_wolo; }
    int stride = gridDim.x * blockDim.x;
    for (int i = blockIdx.x * blockDim.x + threadIdx.x; i < n4; i += stride) {
        float4 f = ((const float4*)src)[i];
        ushort4 h, l;
        h.x = f2bf(f.x); l.x = f2bf(f.x - bf2f(h.x));
        h.y = f2bf(f.y); l.y = f2bf(f.y - bf2f(h.y));
        h.z = f2bf(f.z); l.z = f2bf(f.z - bf2f(h.z));
        h.w = f2bf(f.w); l.w = f2bf(f.w - bf2f(h.w));
        ((ushort4*)hi)[i] = h;
        ((ushort4*)lo)[i] = l;
    }
}

// ------------------------- hi/lo GEMM -------------------------
// WHICH: 0=Q (pre-scaled), 1=K, 2=V (store V^T), 3=output proj -> d_out fp32
// LDS tiles [128 rows][4 chunks of 16B]; chunk position swizzled:
// LDS chunk c holds global chunk c ^ ((row>>1)&3).
template<int WHICH>
__global__ __launch_bounds__(256) void gemm_hilo(float* __restrict__ outf) {
    __shared__ ushort sAh[128*32], sAl[128*32], sBh[128*32], sBl[128*32];

    const ushort* Ahi = (WHICH == 3) ? g_aohi : g_xhi;
    const ushort* Alo = (WHICH == 3) ? g_aolo : g_xlo;
    const ushort* Bhi = (WHICH == 0) ? g_wqhi : (WHICH == 1) ? g_wkhi : (WHICH == 2) ? g_wvhi : g_wohi;
    const ushort* Blo = (WHICH == 0) ? g_wqlo : (WHICH == 1) ? g_wklo : (WHICH == 2) ? g_wvlo : g_wolo;

    const int tid  = threadIdx.x;
    const int lane = tid & 63;
    const int wid  = tid >> 6;
    const int fr   = lane & 15;
    const int fg   = lane >> 4;
    const int n0 = blockIdx.x * 128;
    const int m0 = blockIdx.y * 128;
    const int wm = (wid >> 1) * 64;
    const int wn = (wid & 1) * 64;

    f32x4 acc[4][4];
    const f32x4 zv = {0.f, 0.f, 0.f, 0.f};
#pragma unroll
    for (int i = 0; i < 4; ++i)
#pragma unroll
        for (int j = 0; j < 4; ++j) acc[i][j] = zv;

    for (int k0 = 0; k0 < DMODEL; k0 += 32) {
        __syncthreads();
#pragma unroll
        for (int i = 0; i < 2; ++i) {
            int ch  = tid + i * 256;          // 512 chunks of 16B per buffer
            int row = ch >> 2;
            int c   = ch & 3;
            int cs  = c ^ ((row >> 1) & 3);   // pre-swizzled source chunk
            size_t ga = (size_t)(m0 + row) * DMODEL + k0 + cs * 8;
            size_t gb = (size_t)(n0 + row) * DMODEL + k0 + cs * 8;
            GLDS16(Ahi + ga, (char*)sAh + ch * 16);
            GLDS16(Alo + ga, (char*)sAl + ch * 16);
            GLDS16(Bhi + gb, (char*)sBh + ch * 16);
            GLDS16(Blo + gb, (char*)sBl + ch * 16);
        }
        __syncthreads();

        bf16x8 bh4[4], bl4[4];
#pragma unroll
        for (int nf = 0; nf < 4; ++nf) {
            int r   = wn + nf*16 + fr;
            int off = r * 32 + (fg ^ ((r >> 1) & 3)) * 8;
            bh4[nf] = *(const bf16x8*)&sBh[off];
            bl4[nf] = *(const bf16x8*)&sBl[off];
        }
#pragma unroll
        for (int mf = 0; mf < 4; ++mf) {
            int r   = wm + mf*16 + fr;
            int off = r * 32 + (fg ^ ((r >> 1) & 3)) * 8;
            bf16x8 ah = *(const bf16x8*)&sAh[off];
            bf16x8 al = *(const bf16x8*)&sAl[off];
#pragma unroll
            for (int nf = 0; nf < 4; ++nf) {
                acc[mf][nf] = MFMA16(ah, bh4[nf], acc[mf][nf]);
                acc[mf][nf] = MFMA16(ah, bl4[nf], acc[mf][nf]);
                acc[mf][nf] = MFMA16(al, bh4[nf], acc[mf][nf]);
            }
        }
    }

    // C row = mf*16 + 4*fg + r (token), col = nf*16 + fr (channel)
#pragma unroll
    for (int mf = 0; mf < 4; ++mf)
#pragma unroll
        for (int nf = 0; nf < 4; ++nf)
#pragma unroll
            for (int r = 0; r < 4; ++r) {
                float v = acc[mf][nf][r];
                if (WHICH == 0) v *= 0.18033688011112042f;   // 1/sqrt(64) * log2(e)
                int m = m0 + wm + mf*16 + fg*4 + r;
                int n = n0 + wn + nf*16 + fr;
                if (WHICH == 3) {
                    outf[(size_t)m * DMODEL + n] = v;
                } else {
                    int b = m >> 11, s = m & (SEQ - 1);
                    int h = n >> 6,  d = n & 63;
                    ushort hv = f2bf(v);
                    ushort lv = f2bf(v - bf2f(hv));
                    if (WHICH == 2) {
                        size_t idx = ((size_t)(b*NH + h) * DKH + d) * SEQ + s;
                        g_vthi[idx] = hv; g_vtlo[idx] = lv;
                    } else {
                        size_t idx = ((size_t)(b*NH + h) * SEQ + s) * DKH + d;
                        if (WHICH == 0) { g_qhi[idx] = hv; g_qlo[idx] = lv; }
                        else            { g_khi[idx] = hv; g_klo[idx] = lv; }
                    }
                }
            }
}

// ------------------------- flash attention (causal) -------------------------
// grid (SEQ/64, NBH), 256 thr = 4 waves; wave w owns q rows [q0+16w, q0+16w+16)
// KV tile 64. K LDS [64 kv][64 d], V^T LDS [64 d][64 kv]; both stored linear
// via global_load_lds with 16B-chunk XOR swizzle (c ^ (row&7)) pre-applied to
// the GLOBAL source address; reads apply the same XOR.
__global__ __launch_bounds__(256, 4) void attn_kernel() {
    __shared__ ushort sKh[64*64], sKl[64*64], sVh[64*64], sVl[64*64];  // 32 KB

    const int tid  = threadIdx.x;
    const int lane = tid & 63;
    const int wid  = tid >> 6;
    const int fr   = lane & 15;
    const int fg   = lane >> 4;
    const int q0   = blockIdx.x * 64;
    const int bh   = blockIdx.y;
    const int qw   = q0 + wid * 16;
    const int qs   = qw + fr;
    const size_t qkb = (size_t)bh * SEQ * DKH;
    const size_t vtb = (size_t)bh * DKH * SEQ;

    // Q fragments (B-operand), pre-scaled at projection
    bf16x8 Qh[2], Ql[2];
#pragma unroll
    for (int dh = 0; dh < 2; ++dh) {
        size_t o = qkb + (size_t)(qw + fr) * DKH + fg * 8 + dh * 32;
        Qh[dh] = *(const bf16x8*)(g_qhi + o);
        Ql[dh] = *(const bf16x8*)(g_qlo + o);
    }

    float m_run = -1e30f, l_run = 0.f;
    f32x4 accO[4];
    const f32x4 zv = {0.f, 0.f, 0.f, 0.f};
#pragma unroll
    for (int i = 0; i < 4; ++i) accO[i] = zv;

    const int nt = (q0 + 64) / 64;   // tiles of 64 kv
    for (int t = 0; t < nt; ++t) {
        const int kv0 = t * 64;
        __syncthreads();
        {   // stage: 2 chunks per array per thread, dest linear, source pre-swizzled
#pragma unroll
            for (int i = 0; i < 2; ++i) {
                int ch = tid + i * 256;          // 0..511
                int r  = ch >> 3;                // row (kv for K, d for V)
                int c  = ch & 7;                 // 16B chunk in row
                int ck = c ^ (r & 7);
                size_t gk = qkb + (size_t)(kv0 + r) * DKH + ck * 8;
                size_t gv = vtb + (size_t)r * SEQ + kv0 + ck * 8;
                GLDS16(g_khi  + gk, (char*)sKh + ch * 16);
                GLDS16(g_klo  + gk, (char*)sKl + ch * 16);
                GLDS16(g_vthi + gv, (char*)sVh + ch * 16);
                GLDS16(g_vtlo + gv, (char*)sVl + ch * 16);
            }
        }
        __syncthreads();

        if (kv0 > qw + 15) continue;   // wave-uniform

        // ---- scores accS[kg]: D[kv][q], kv = kv0+16kg+4fg+r, q = fr
        f32x4 accS[4] = { zv, zv, zv, zv };
#pragma unroll
        for (int kg = 0; kg < 4; ++kg) {
            if (kv0 + kg*16 <= qw + 15) {
                int rowb = (kg*16 + fr) * 128;
                int fs = (fr & 7);
#pragma unroll
                for (int dh = 0; dh < 2; ++dh) {
                    int cb = ((fg + 4*dh) ^ fs) * 16;
                    bf16x8 kh = *(const bf16x8*)((const char*)sKh + rowb + cb);
                    bf16x8 kl = *(const bf16x8*)((const char*)sKl + rowb + cb);
                    accS[kg] = MFMA16(kh, Qh[dh], accS[kg]);
                    accS[kg] = MFMA16(kh, Ql[dh], accS[kg]);
                    accS[kg] = MFMA16(kl, Qh[dh], accS[kg]);
                }
            }
        }

        // ---- online softmax (scores already include 1/8*log2e)
        float p[16];
        float mt = -1e30f;
#pragma unroll
        for (int kg = 0; kg < 4; ++kg)
#pragma unroll
            for (int r = 0; r < 4; ++r) {
                float s = accS[kg][r];
                int kv = kv0 + kg*16 + fg*4 + r;
                if (kv > qs) s = -1e30f;
                p[kg*4 + r] = s;
                mt = fmaxf(mt, s);
            }
        mt = fmaxf(mt, __shfl_xor(mt, 16));
        mt = fmaxf(mt, __shfl_xor(mt, 32));
        float mn   = fmaxf(m_run, mt);
        float corr = exp2f(m_run - mn);
        float rs = 0.f;
#pragma unroll
        for (int i = 0; i < 16; ++i) { p[i] = exp2f(p[i] - mn); rs += p[i]; }
        rs += __shfl_xor(rs, 16);
        rs += __shfl_xor(rs, 32);
        l_run = l_run * corr + rs;
        m_run = mn;

        float c4[4];
#pragma unroll
        for (int r = 0; r < 4; ++r) c4[r] = __shfl(corr, fg*4 + r);
#pragma unroll
        for (int ds = 0; ds < 4; ++ds)
#pragma unroll
            for (int r = 0; r < 4; ++r) accO[ds][r] *= c4[r];

        // ---- PV over two 32-kv halves
#pragma unroll
        for (int kh2 = 0; kh2 < 2; ++kh2) {
            if (kv0 + kh2*32 > qw + 15) break;   // wave-uniform
            bf16x8 ph, pl;
#pragma unroll
            for (int i = 0; i < 8; ++i) {
                float pv = p[(2*kh2 + (i>>2))*4 + (i&3)];
                ushort h = f2bf(pv);
                ph[i] = (short)h;
                pl[i] = (short)f2bf(pv - bf2f(h));
            }
#pragma unroll
            for (int ds = 0; ds < 4; ++ds) {
                int d = ds*16 + fr;
                int rowb = d * 128;
                int fs = (fr & 7);
                int c1 = (((4*kh2 +     (fg>>1)) ^ fs) << 4) + (fg & 1) * 8;
                int c2 = (((4*kh2 + 2 + (fg>>1)) ^ fs) << 4) + (fg & 1) * 8;
                union { bf16x8 v; uint2 u[2]; } Vhh, Vll;
                Vhh.u[0] = *(const uint2*)((const char*)sVh + rowb + c1);
                Vhh.u[1] = *(const uint2*)((const char*)sVh + rowb + c2);
                Vll.u[0] = *(const uint2*)((const char*)sVl + rowb + c1);
                Vll.u[1] = *(const uint2*)((const char*)sVl + rowb + c2);
                accO[ds] = MFMA16(ph, Vhh.v, accO[ds]);
                accO[ds] = MFMA16(ph, Vll.v, accO[ds]);
                accO[ds] = MFMA16(pl, Vhh.v, accO[ds]);
            }
        }
    }

    // ---- epilogue
    float l4[4];
#pragma unroll
    for (int r = 0; r < 4; ++r) l4[r] = 1.0f / __shfl(l_run, fg*4 + r);
#pragma unroll
    for (int ds = 0; ds < 4; ++ds)
#pragma unroll
        for (int r = 0; r < 4; ++r) {
            float v = accO[ds][r] * l4[r];
            int q   = qw + fg*4 + r;
            int tkn = (bh >> 4) * SEQ + q;
            int col = (bh & 15) * DKH + ds*16 + fr;
            size_t idx = (size_t)tkn * DMODEL + col;
            ushort hv = f2bf(v);
            g_aohi[idx] = hv;
            g_aolo[idx] = f2bf(v - bf2f(hv));
        }
}

// ------------------------- launcher -------------------------
extern "C" void kernel_launch(void* const* d_in, const int* in_sizes, int n_in,
                              void* d_out, int out_size, void* d_ws, size_t ws_size,
                              hipStream_t stream) {
    const float* x  = (const float*)d_in[0];
    const float* wq = (const float*)d_in[1];
    const float* wk = (const float*)d_in[2];
    const float* wv = (const float*)d_in[3];
    const float* wo = (const float*)d_in[4];
    float* out = (float*)d_out;

    cvt_hilo<0><<<2048, 256, 0, stream>>>(x,  (NT*DMODEL)/4);
    cvt_hilo<1><<<512,  256, 0, stream>>>(wq, (DMODEL*DMODEL)/4);
    cvt_hilo<2><<<512,  256, 0, stream>>>(wk, (DMODEL*DMODEL)/4);
    cvt_hilo<3><<<512,  256, 0, stream>>>(wv, (DMODEL*DMODEL)/4);
    cvt_hilo<4><<<512,  256, 0, stream>>>(wo, (DMODEL*DMODEL)/4);

    dim3 gg(DMODEL/128, NT/128);
    gemm_hilo<0><<<gg, 256, 0, stream>>>(out);
    gemm_hilo<1><<<gg, 256, 0, stream>>>(out);
    gemm_hilo<2><<<gg, 256, 0, stream>>>(out);

    attn_kernel<<<dim3(SEQ/64, NBH), 256, 0, stream>>>();

    gemm_hilo<3><<<gg, 256, 0, stream>>>(out);
}

// Round 6
// 654.580 us; speedup vs baseline: 1.2230x; 1.0559x over previous
//
#include <hip/hip_runtime.h>

// ---------------------------------------------------------------------------
// MultiheadSelfAttention fp32 via hi/lo bf16 split (3-MFMA emulation).
// R6 = R5 resubmit (infra timeout; never benched):
//   attn QBLK=128 w/ 8 waves (half the K/V restaging, 32 waves/CU),
//   GEMM XCD-aware block swizzle (A-panel L2 locality), V^T packed stores.
// ---------------------------------------------------------------------------

#define DMODEL 1024
#define NH 16
#define DKH 64
#define NB 4
#define SEQ 2048
#define NT (NB*SEQ)   // 8192 tokens
#define NBH (NB*NH)   // 64

typedef __attribute__((ext_vector_type(8))) short bf16x8;
typedef __attribute__((ext_vector_type(4))) float f32x4;
typedef unsigned int u32;

#define MFMA16(a, b, c) __builtin_amdgcn_mfma_f32_16x16x32_bf16((a), (b), (c), 0, 0, 0)
#define GLDS16(gp, lp) \
    __builtin_amdgcn_global_load_lds((const __attribute__((address_space(1))) u32*)(const void*)(gp), \
                                     (__attribute__((address_space(3))) u32*)(void*)(lp), 16, 0, 0)

// ------------------------- device scratch -------------------------
__device__ ushort g_xhi[NT*DMODEL],  g_xlo[NT*DMODEL];
__device__ ushort g_wqhi[DMODEL*DMODEL], g_wqlo[DMODEL*DMODEL];
__device__ ushort g_wkhi[DMODEL*DMODEL], g_wklo[DMODEL*DMODEL];
__device__ ushort g_wvhi[DMODEL*DMODEL], g_wvlo[DMODEL*DMODEL];
__device__ ushort g_wohi[DMODEL*DMODEL], g_wolo[DMODEL*DMODEL];
__device__ ushort g_qhi[NBH*SEQ*DKH],  g_qlo[NBH*SEQ*DKH];    // pre-scaled by 1/8*log2e
__device__ ushort g_khi[NBH*SEQ*DKH],  g_klo[NBH*SEQ*DKH];
__device__ ushort g_vthi[NBH*DKH*SEQ], g_vtlo[NBH*DKH*SEQ];   // V^T: [bh][d][s]
__device__ ushort g_aohi[NT*DMODEL],   g_aolo[NT*DMODEL];

// ------------------------- helpers -------------------------
static __device__ __forceinline__ ushort f2bf(float f) {
    unsigned u = __float_as_uint(f);
    return (ushort)((u + 0x7fffu + ((u >> 16) & 1u)) >> 16);
}
static __device__ __forceinline__ float bf2f(ushort h) {
    return __uint_as_float(((unsigned)h) << 16);
}

// ------------------------- fp32 -> (hi,lo) bf16 -------------------------
template<int DST>
__global__ void cvt_hilo(const float* __restrict__ src, int n4) {
    ushort* hi; ushort* lo;
    if      (DST == 0) { hi = g_xhi;  lo = g_xlo;  }
    else if (DST == 1) { hi = g_wqhi; lo = g_wqlo; }
    else if (DST == 2) { hi = g_wkhi; lo = g_wklo; }
    else if (DST == 3) { hi = g_wvhi; lo = g_wvlo; }
    else               { hi = g_wohi; lo = g_wolo; }
    int stride = gridDim.x * blockDim.x;
    for (int i = blockIdx.x * blockDim.x + threadIdx.x; i < n4; i += stride) {
        float4 f = ((const float4*)src)[i];
        ushort4 h, l;
        h.x = f2bf(f.x); l.x = f2bf(f.x - bf2f(h.x));
        h.y = f2bf(f.y); l.y = f2bf(f.y - bf2f(h.y));
        h.z = f2bf(f.z); l.z = f2bf(f.z - bf2f(h.z));
        h.w = f2bf(f.w); l.w = f2bf(f.w - bf2f(h.w));
        ((ushort4*)hi)[i] = h;
        ((ushort4*)lo)[i] = l;
    }
}

// ------------------------- hi/lo GEMM -------------------------
// WHICH: 0=Q (pre-scaled), 1=K, 2=V (store V^T), 3=output proj -> d_out fp32
// Flat grid 512; XCD swizzle: id&7 = XCD -> each XCD owns 8 consecutive
// m-panels so the A panel is fetched once per XCD (A >> B traffic).
// LDS tiles [128 rows][4 chunks of 16B]; chunk c holds global chunk
// c ^ ((row>>1)&3) (fragment ds_read_b128 8-way -> 2-way banks).
template<int WHICH>
__global__ __launch_bounds__(256) void gemm_hilo(float* __restrict__ outf) {
    __shared__ ushort sAh[128*32], sAl[128*32], sBh[128*32], sBl[128*32];

    const ushort* Ahi = (WHICH == 3) ? g_aohi : g_xhi;
    const ushort* Alo = (WHICH == 3) ? g_aolo : g_xlo;
    const ushort* Bhi = (WHICH == 0) ? g_wqhi : (WHICH == 1) ? g_wkhi : (WHICH == 2) ? g_wvhi : g_wohi;
    const ushort* Blo = (WHICH == 0) ? g_wqlo : (WHICH == 1) ? g_wklo : (WHICH == 2) ? g_wvlo : g_wolo;

    const int tid  = threadIdx.x;
    const int lane = tid & 63;
    const int wid  = tid >> 6;
    const int fr   = lane & 15;
    const int fg   = lane >> 4;
    // bijective XCD-aware remap of 512 blocks (8 n-panels x 64 m-panels)
    const int id  = blockIdx.x;
    const int jj  = id >> 3;
    const int n0  = (jj & 7) * 128;
    const int m0  = ((id & 7) * 8 + (jj >> 3)) * 128;
    const int wm = (wid >> 1) * 64;
    const int wn = (wid & 1) * 64;

    f32x4 acc[4][4];
    const f32x4 zv = {0.f, 0.f, 0.f, 0.f};
#pragma unroll
    for (int i = 0; i < 4; ++i)
#pragma unroll
        for (int j = 0; j < 4; ++j) acc[i][j] = zv;

    for (int k0 = 0; k0 < DMODEL; k0 += 32) {
        __syncthreads();
#pragma unroll
        for (int i = 0; i < 2; ++i) {
            int ch  = tid + i * 256;          // 512 chunks of 16B per buffer
            int row = ch >> 2;
            int c   = ch & 3;
            int cs  = c ^ ((row >> 1) & 3);   // pre-swizzled source chunk
            size_t ga = (size_t)(m0 + row) * DMODEL + k0 + cs * 8;
            size_t gb = (size_t)(n0 + row) * DMODEL + k0 + cs * 8;
            GLDS16(Ahi + ga, (char*)sAh + ch * 16);
            GLDS16(Alo + ga, (char*)sAl + ch * 16);
            GLDS16(Bhi + gb, (char*)sBh + ch * 16);
            GLDS16(Blo + gb, (char*)sBl + ch * 16);
        }
        __syncthreads();

        bf16x8 bh4[4], bl4[4];
#pragma unroll
        for (int nf = 0; nf < 4; ++nf) {
            int r   = wn + nf*16 + fr;
            int off = r * 32 + (fg ^ ((r >> 1) & 3)) * 8;
            bh4[nf] = *(const bf16x8*)&sBh[off];
            bl4[nf] = *(const bf16x8*)&sBl[off];
        }
#pragma unroll
        for (int mf = 0; mf < 4; ++mf) {
            int r   = wm + mf*16 + fr;
            int off = r * 32 + (fg ^ ((r >> 1) & 3)) * 8;
            bf16x8 ah = *(const bf16x8*)&sAh[off];
            bf16x8 al = *(const bf16x8*)&sAl[off];
#pragma unroll
            for (int nf = 0; nf < 4; ++nf) {
                acc[mf][nf] = MFMA16(ah, bh4[nf], acc[mf][nf]);
                acc[mf][nf] = MFMA16(ah, bl4[nf], acc[mf][nf]);
                acc[mf][nf] = MFMA16(al, bh4[nf], acc[mf][nf]);
            }
        }
    }

    // C row = mf*16 + 4*fg + r (token), col = nf*16 + fr (channel)
#pragma unroll
    for (int mf = 0; mf < 4; ++mf)
#pragma unroll
        for (int nf = 0; nf < 4; ++nf) {
            if (WHICH == 2) {
                // V^T: 4 consecutive s per reg -> one ushort4 store per array
                ushort4 hv4, lv4;
#pragma unroll
                for (int r = 0; r < 4; ++r) {
                    float v = acc[mf][nf][r];
                    ushort hv = f2bf(v);
                    ((ushort*)&hv4)[r] = hv;
                    ((ushort*)&lv4)[r] = f2bf(v - bf2f(hv));
                }
                int m = m0 + wm + mf*16 + fg*4;      // token of r=0 (mult of 4)
                int n = n0 + wn + nf*16 + fr;
                int b = m >> 11, s = m & (SEQ - 1);
                int h = n >> 6,  d = n & 63;
                size_t idx = ((size_t)(b*NH + h) * DKH + d) * SEQ + s;
                *(ushort4*)(g_vthi + idx) = hv4;
                *(ushort4*)(g_vtlo + idx) = lv4;
            } else {
#pragma unroll
                for (int r = 0; r < 4; ++r) {
                    float v = acc[mf][nf][r];
                    if (WHICH == 0) v *= 0.18033688011112042f;   // 1/8 * log2(e)
                    int m = m0 + wm + mf*16 + fg*4 + r;
                    int n = n0 + wn + nf*16 + fr;
                    if (WHICH == 3) {
                        outf[(size_t)m * DMODEL + n] = v;
                    } else {
                        int b = m >> 11, s = m & (SEQ - 1);
                        int h = n >> 6,  d = n & 63;
                        ushort hv = f2bf(v);
                        ushort lv = f2bf(v - bf2f(hv));
                        size_t idx = ((size_t)(b*NH + h) * SEQ + s) * DKH + d;
                        if (WHICH == 0) { g_qhi[idx] = hv; g_qlo[idx] = lv; }
                        else            { g_khi[idx] = hv; g_klo[idx] = lv; }
                    }
                }
            }
        }
}

// ------------------------- flash attention (causal) -------------------------
// grid (SEQ/128, NBH), 512 thr = 8 waves; wave w owns q rows [q0+16w, q0+16w+16)
// KV tile 64. K LDS [64 kv][64 d], V^T LDS [64 d][64 kv]; stored linear via
// global_load_lds, 16B-chunk XOR swizzle (c ^ (row&7)) pre-applied to the
// GLOBAL source address; reads apply the same XOR.
__global__ __launch_bounds__(512, 4) void attn_kernel() {
    __shared__ ushort sKh[64*64], sKl[64*64], sVh[64*64], sVl[64*64];  // 32 KB

    const int tid  = threadIdx.x;
    const int lane = tid & 63;
    const int wid  = tid >> 6;          // 0..7
    const int fr   = lane & 15;
    const int fg   = lane >> 4;
    const int q0   = blockIdx.x * 128;
    const int bh   = blockIdx.y;
    const int qw   = q0 + wid * 16;
    const int qs   = qw + fr;
    const size_t qkb = (size_t)bh * SEQ * DKH;
    const size_t vtb = (size_t)bh * DKH * SEQ;

    // Q fragments (B-operand), pre-scaled at projection
    bf16x8 Qh[2], Ql[2];
#pragma unroll
    for (int dh = 0; dh < 2; ++dh) {
        size_t o = qkb + (size_t)(qw + fr) * DKH + fg * 8 + dh * 32;
        Qh[dh] = *(const bf16x8*)(g_qhi + o);
        Ql[dh] = *(const bf16x8*)(g_qlo + o);
    }

    float m_run = -1e30f, l_run = 0.f;
    f32x4 accO[4];
    const f32x4 zv = {0.f, 0.f, 0.f, 0.f};
#pragma unroll
    for (int i = 0; i < 4; ++i) accO[i] = zv;

    const int nt = (q0 + 128) / 64;   // tiles of 64 kv
    for (int t = 0; t < nt; ++t) {
        const int kv0 = t * 64;
        __syncthreads();
        {   // stage: 1 chunk per array per thread (512 thr), source pre-swizzled
            int ch = tid;                    // 0..511
            int r  = ch >> 3;                // row (kv for K, d for V)
            int c  = ch & 7;                 // 16B chunk in row
            int ck = c ^ (r & 7);
            size_t gk = qkb + (size_t)(kv0 + r) * DKH + ck * 8;
            size_t gv = vtb + (size_t)r * SEQ + kv0 + ck * 8;
            GLDS16(g_khi  + gk, (char*)sKh + ch * 16);
            GLDS16(g_klo  + gk, (char*)sKl + ch * 16);
            GLDS16(g_vthi + gv, (char*)sVh + ch * 16);
            GLDS16(g_vtlo + gv, (char*)sVl + ch * 16);
        }
        __syncthreads();

        if (kv0 > qw + 15) continue;   // wave-uniform: fully masked for this wave

        // ---- scores accS[kg]: D[kv][q], kv = kv0+16kg+4fg+r, q = fr
        f32x4 accS[4] = { zv, zv, zv, zv };
#pragma unroll
        for (int kg = 0; kg < 4; ++kg) {
            if (kv0 + kg*16 <= qw + 15) {
                int rowb = (kg*16 + fr) * 128;
                int fs = (fr & 7);
#pragma unroll
                for (int dh = 0; dh < 2; ++dh) {
                    int cb = ((fg + 4*dh) ^ fs) * 16;
                    bf16x8 kh = *(const bf16x8*)((const char*)sKh + rowb + cb);
                    bf16x8 kl = *(const bf16x8*)((const char*)sKl + rowb + cb);
                    accS[kg] = MFMA16(kh, Qh[dh], accS[kg]);
                    accS[kg] = MFMA16(kh, Ql[dh], accS[kg]);
                    accS[kg] = MFMA16(kl, Qh[dh], accS[kg]);
                }
            }
        }

        // ---- online softmax (scores already include 1/8*log2e)
        float p[16];
        float mt = -1e30f;
#pragma unroll
        for (int kg = 0; kg < 4; ++kg)
#pragma unroll
            for (int r = 0; r < 4; ++r) {
                float s = accS[kg][r];
                int kv = kv0 + kg*16 + fg*4 + r;
                if (kv > qs) s = -1e30f;
                p[kg*4 + r] = s;
                mt = fmaxf(mt, s);
            }
        mt = fmaxf(mt, __shfl_xor(mt, 16));
        mt = fmaxf(mt, __shfl_xor(mt, 32));
        float mn   = fmaxf(m_run, mt);
        float corr = exp2f(m_run - mn);
        float rs = 0.f;
#pragma unroll
        for (int i = 0; i < 16; ++i) { p[i] = exp2f(p[i] - mn); rs += p[i]; }
        rs += __shfl_xor(rs, 16);
        rs += __shfl_xor(rs, 32);
        l_run = l_run * corr + rs;
        m_run = mn;

        float c4[4];
#pragma unroll
        for (int r = 0; r < 4; ++r) c4[r] = __shfl(corr, fg*4 + r);
#pragma unroll
        for (int ds = 0; ds < 4; ++ds)
#pragma unroll
            for (int r = 0; r < 4; ++r) accO[ds][r] *= c4[r];

        // ---- PV over two 32-kv halves
#pragma unroll
        for (int kh2 = 0; kh2 < 2; ++kh2) {
            if (kv0 + kh2*32 > qw + 15) break;   // wave-uniform
            bf16x8 ph, pl;
#pragma unroll
            for (int i = 0; i < 8; ++i) {
                float pv = p[(2*kh2 + (i>>2))*4 + (i&3)];
                ushort h = f2bf(pv);
                ph[i] = (short)h;
                pl[i] = (short)f2bf(pv - bf2f(h));
            }
#pragma unroll
            for (int ds = 0; ds < 4; ++ds) {
                int d = ds*16 + fr;
                int rowb = d * 128;
                int fs = (fr & 7);
                int c1 = (((4*kh2 +     (fg>>1)) ^ fs) << 4) + (fg & 1) * 8;
                int c2 = (((4*kh2 + 2 + (fg>>1)) ^ fs) << 4) + (fg & 1) * 8;
                union { bf16x8 v; uint2 u[2]; } Vhh, Vll;
                Vhh.u[0] = *(const uint2*)((const char*)sVh + rowb + c1);
                Vhh.u[1] = *(const uint2*)((const char*)sVh + rowb + c2);
                Vll.u[0] = *(const uint2*)((const char*)sVl + rowb + c1);
                Vll.u[1] = *(const uint2*)((const char*)sVl + rowb + c2);
                accO[ds] = MFMA16(ph, Vhh.v, accO[ds]);
                accO[ds] = MFMA16(ph, Vll.v, accO[ds]);
                accO[ds] = MFMA16(pl, Vhh.v, accO[ds]);
            }
        }
    }

    // ---- epilogue
    float l4[4];
#pragma unroll
    for (int r = 0; r < 4; ++r) l4[r] = 1.0f / __shfl(l_run, fg*4 + r);
#pragma unroll
    for (int ds = 0; ds < 4; ++ds)
#pragma unroll
        for (int r = 0; r < 4; ++r) {
            float v = accO[ds][r] * l4[r];
            int q   = qw + fg*4 + r;
            int tkn = (bh >> 4) * SEQ + q;
            int col = (bh & 15) * DKH + ds*16 + fr;
            size_t idx = (size_t)tkn * DMODEL + col;
            ushort hv = f2bf(v);
            g_aohi[idx] = hv;
            g_aolo[idx] = f2bf(v - bf2f(hv));
        }
}

// ------------------------- launcher -------------------------
extern "C" void kernel_launch(void* const* d_in, const int* in_sizes, int n_in,
                              void* d_out, int out_size, void* d_ws, size_t ws_size,
                              hipStream_t stream) {
    const float* x  = (const float*)d_in[0];
    const float* wq = (const float*)d_in[1];
    const float* wk = (const float*)d_in[2];
    const float* wv = (const float*)d_in[3];
    const float* wo = (const float*)d_in[4];
    float* out = (float*)d_out;

    cvt_hilo<0><<<2048, 256, 0, stream>>>(x,  (NT*DMODEL)/4);
    cvt_hilo<1><<<512,  256, 0, stream>>>(wq, (DMODEL*DMODEL)/4);
    cvt_hilo<2><<<512,  256, 0, stream>>>(wk, (DMODEL*DMODEL)/4);
    cvt_hilo<3><<<512,  256, 0, stream>>>(wv, (DMODEL*DMODEL)/4);
    cvt_hilo<4><<<512,  256, 0, stream>>>(wo, (DMODEL*DMODEL)/4);

    const int NBLK = (DMODEL/128) * (NT/128);   // 512
    gemm_hilo<0><<<NBLK, 256, 0, stream>>>(out);
    gemm_hilo<1><<<NBLK, 256, 0, stream>>>(out);
    gemm_hilo<2><<<NBLK, 256, 0, stream>>>(out);

    attn_kernel<<<dim3(SEQ/128, NBH), 512, 0, stream>>>();

    gemm_hilo<3><<<NBLK, 256, 0, stream>>>(out);
}

// Round 7
// 525.899 us; speedup vs baseline: 1.5223x; 1.2447x over previous
//
#include <hip/hip_runtime.h>
#include <hip/hip_bf16.h>

// ---------------------------------------------------------------------------
// MultiheadSelfAttention fp32 via hi/lo bf16 split (3-MFMA emulation).
// R7: causal load-balancing (block handles qb and 15-qb -> constant 34 tiles
//     per block), HW v_cvt bf16 conversions, mask-skip on interior tiles.
// ---------------------------------------------------------------------------

#define DMODEL 1024
#define NH 16
#define DKH 64
#define NB 4
#define SEQ 2048
#define NT (NB*SEQ)   // 8192 tokens
#define NBH (NB*NH)   // 64
#define NQB (SEQ/128) // 16 q-blocks per bh

typedef __attribute__((ext_vector_type(8))) short bf16x8;
typedef __attribute__((ext_vector_type(4))) float f32x4;
typedef unsigned int u32;

#define MFMA16(a, b, c) __builtin_amdgcn_mfma_f32_16x16x32_bf16((a), (b), (c), 0, 0, 0)
#define GLDS16(gp, lp) \
    __builtin_amdgcn_global_load_lds((const __attribute__((address_space(1))) u32*)(const void*)(gp), \
                                     (__attribute__((address_space(3))) u32*)(void*)(lp), 16, 0, 0)

// ------------------------- device scratch -------------------------
__device__ ushort g_xhi[NT*DMODEL],  g_xlo[NT*DMODEL];
__device__ ushort g_wqhi[DMODEL*DMODEL], g_wqlo[DMODEL*DMODEL];
__device__ ushort g_wkhi[DMODEL*DMODEL], g_wklo[DMODEL*DMODEL];
__device__ ushort g_wvhi[DMODEL*DMODEL], g_wvlo[DMODEL*DMODEL];
__device__ ushort g_wohi[DMODEL*DMODEL], g_wolo[DMODEL*DMODEL];
__device__ ushort g_qhi[NBH*SEQ*DKH],  g_qlo[NBH*SEQ*DKH];    // pre-scaled by 1/8*log2e
__device__ ushort g_khi[NBH*SEQ*DKH],  g_klo[NBH*SEQ*DKH];
__device__ ushort g_vthi[NBH*DKH*SEQ], g_vtlo[NBH*DKH*SEQ];   // V^T: [bh][d][s]
__device__ ushort g_aohi[NT*DMODEL],   g_aolo[NT*DMODEL];

// ------------------------- helpers -------------------------
static __device__ __forceinline__ ushort f2bf(float f) {   // HW v_cvt, RNE
    union { __hip_bfloat16 b; ushort u; } cv;
    cv.b = __float2bfloat16(f);
    return cv.u;
}
static __device__ __forceinline__ float bf2f(ushort h) {
    return __uint_as_float(((unsigned)h) << 16);
}

// ------------------------- fp32 -> (hi,lo) bf16 -------------------------
template<int DST>
__global__ void cvt_hilo(const float* __restrict__ src, int n4) {
    ushort* hi; ushort* lo;
    if      (DST == 0) { hi = g_xhi;  lo = g_xlo;  }
    else if (DST == 1) { hi = g_wqhi; lo = g_wqlo; }
    else if (DST == 2) { hi = g_wkhi; lo = g_wklo; }
    else if (DST == 3) { hi = g_wvhi; lo = g_wvlo; }
    else               { hi = g_wohi; lo = g_wolo; }
    int stride = gridDim.x * blockDim.x;
    for (int i = blockIdx.x * blockDim.x + threadIdx.x; i < n4; i += stride) {
        float4 f = ((const float4*)src)[i];
        ushort4 h, l;
        h.x = f2bf(f.x); l.x = f2bf(f.x - bf2f(h.x));
        h.y = f2bf(f.y); l.y = f2bf(f.y - bf2f(h.y));
        h.z = f2bf(f.z); l.z = f2bf(f.z - bf2f(h.z));
        h.w = f2bf(f.w); l.w = f2bf(f.w - bf2f(h.w));
        ((ushort4*)hi)[i] = h;
        ((ushort4*)lo)[i] = l;
    }
}

// ------------------------- hi/lo GEMM -------------------------
// WHICH: 0=Q (pre-scaled), 1=K, 2=V (store V^T), 3=output proj -> d_out fp32
// Flat grid 512; XCD swizzle: id&7 = XCD -> each XCD owns 8 consecutive
// m-panels so the A panel is fetched once per XCD (A >> B traffic).
// LDS tiles [128 rows][4 chunks of 16B]; chunk c holds global chunk
// c ^ ((row>>1)&3) (fragment ds_read_b128 8-way -> 2-way banks).
template<int WHICH>
__global__ __launch_bounds__(256) void gemm_hilo(float* __restrict__ outf) {
    __shared__ ushort sAh[128*32], sAl[128*32], sBh[128*32], sBl[128*32];

    const ushort* Ahi = (WHICH == 3) ? g_aohi : g_xhi;
    const ushort* Alo = (WHICH == 3) ? g_aolo : g_xlo;
    const ushort* Bhi = (WHICH == 0) ? g_wqhi : (WHICH == 1) ? g_wkhi : (WHICH == 2) ? g_wvhi : g_wohi;
    const ushort* Blo = (WHICH == 0) ? g_wqlo : (WHICH == 1) ? g_wklo : (WHICH == 2) ? g_wvlo : g_wolo;

    const int tid  = threadIdx.x;
    const int lane = tid & 63;
    const int wid  = tid >> 6;
    const int fr   = lane & 15;
    const int fg   = lane >> 4;
    // bijective XCD-aware remap of 512 blocks (8 n-panels x 64 m-panels)
    const int id  = blockIdx.x;
    const int jj  = id >> 3;
    const int n0  = (jj & 7) * 128;
    const int m0  = ((id & 7) * 8 + (jj >> 3)) * 128;
    const int wm = (wid >> 1) * 64;
    const int wn = (wid & 1) * 64;

    f32x4 acc[4][4];
    const f32x4 zv = {0.f, 0.f, 0.f, 0.f};
#pragma unroll
    for (int i = 0; i < 4; ++i)
#pragma unroll
        for (int j = 0; j < 4; ++j) acc[i][j] = zv;

    for (int k0 = 0; k0 < DMODEL; k0 += 32) {
        __syncthreads();
#pragma unroll
        for (int i = 0; i < 2; ++i) {
            int ch  = tid + i * 256;          // 512 chunks of 16B per buffer
            int row = ch >> 2;
            int c   = ch & 3;
            int cs  = c ^ ((row >> 1) & 3);   // pre-swizzled source chunk
            size_t ga = (size_t)(m0 + row) * DMODEL + k0 + cs * 8;
            size_t gb = (size_t)(n0 + row) * DMODEL + k0 + cs * 8;
            GLDS16(Ahi + ga, (char*)sAh + ch * 16);
            GLDS16(Alo + ga, (char*)sAl + ch * 16);
            GLDS16(Bhi + gb, (char*)sBh + ch * 16);
            GLDS16(Blo + gb, (char*)sBl + ch * 16);
        }
        __syncthreads();

        bf16x8 bh4[4], bl4[4];
#pragma unroll
        for (int nf = 0; nf < 4; ++nf) {
            int r   = wn + nf*16 + fr;
            int off = r * 32 + (fg ^ ((r >> 1) & 3)) * 8;
            bh4[nf] = *(const bf16x8*)&sBh[off];
            bl4[nf] = *(const bf16x8*)&sBl[off];
        }
#pragma unroll
        for (int mf = 0; mf < 4; ++mf) {
            int r   = wm + mf*16 + fr;
            int off = r * 32 + (fg ^ ((r >> 1) & 3)) * 8;
            bf16x8 ah = *(const bf16x8*)&sAh[off];
            bf16x8 al = *(const bf16x8*)&sAl[off];
#pragma unroll
            for (int nf = 0; nf < 4; ++nf) {
                acc[mf][nf] = MFMA16(ah, bh4[nf], acc[mf][nf]);
                acc[mf][nf] = MFMA16(ah, bl4[nf], acc[mf][nf]);
                acc[mf][nf] = MFMA16(al, bh4[nf], acc[mf][nf]);
            }
        }
    }

    // C row = mf*16 + 4*fg + r (token), col = nf*16 + fr (channel)
#pragma unroll
    for (int mf = 0; mf < 4; ++mf)
#pragma unroll
        for (int nf = 0; nf < 4; ++nf) {
            if (WHICH == 2) {
                // V^T: 4 consecutive s per reg -> one ushort4 store per array
                ushort4 hv4, lv4;
#pragma unroll
                for (int r = 0; r < 4; ++r) {
                    float v = acc[mf][nf][r];
                    ushort hv = f2bf(v);
                    ((ushort*)&hv4)[r] = hv;
                    ((ushort*)&lv4)[r] = f2bf(v - bf2f(hv));
                }
                int m = m0 + wm + mf*16 + fg*4;      // token of r=0 (mult of 4)
                int n = n0 + wn + nf*16 + fr;
                int b = m >> 11, s = m & (SEQ - 1);
                int h = n >> 6,  d = n & 63;
                size_t idx = ((size_t)(b*NH + h) * DKH + d) * SEQ + s;
                *(ushort4*)(g_vthi + idx) = hv4;
                *(ushort4*)(g_vtlo + idx) = lv4;
            } else {
#pragma unroll
                for (int r = 0; r < 4; ++r) {
                    float v = acc[mf][nf][r];
                    if (WHICH == 0) v *= 0.18033688011112042f;   // 1/8 * log2(e)
                    int m = m0 + wm + mf*16 + fg*4 + r;
                    int n = n0 + wn + nf*16 + fr;
                    if (WHICH == 3) {
                        outf[(size_t)m * DMODEL + n] = v;
                    } else {
                        int b = m >> 11, s = m & (SEQ - 1);
                        int h = n >> 6,  d = n & 63;
                        ushort hv = f2bf(v);
                        ushort lv = f2bf(v - bf2f(hv));
                        size_t idx = ((size_t)(b*NH + h) * SEQ + s) * DKH + d;
                        if (WHICH == 0) { g_qhi[idx] = hv; g_qlo[idx] = lv; }
                        else            { g_khi[idx] = hv; g_klo[idx] = lv; }
                    }
                }
            }
        }
}

// ------------------------- flash attention (causal) -------------------------
// grid (NQB/2, NBH), 512 thr = 8 waves. Causal load balance: block bx handles
// q-blocks {bx, NQB-1-bx} sequentially -> every block does exactly 34 KV
// tiles; 512 blocks = 2/CU, all resident, no straggler tail.
// KV tile 64. K LDS [64 kv][64 d], V^T LDS [64 d][64 kv]; stored linear via
// global_load_lds, 16B-chunk XOR swizzle (c ^ (row&7)) pre-applied to the
// GLOBAL source address; reads apply the same XOR.
__global__ __launch_bounds__(512, 4) void attn_kernel() {
    __shared__ ushort sKh[64*64], sKl[64*64], sVh[64*64], sVl[64*64];  // 32 KB

    const int tid  = threadIdx.x;
    const int lane = tid & 63;
    const int wid  = tid >> 6;          // 0..7
    const int fr   = lane & 15;
    const int fg   = lane >> 4;
    const int bh   = blockIdx.y;
    const size_t qkb = (size_t)bh * SEQ * DKH;
    const size_t vtb = (size_t)bh * DKH * SEQ;
    const f32x4 zv = {0.f, 0.f, 0.f, 0.f};

    for (int pass = 0; pass < 2; ++pass) {
        const int qb = pass ? (NQB - 1 - (int)blockIdx.x) : (int)blockIdx.x;
        const int q0 = qb * 128;
        const int qw = q0 + wid * 16;
        const int qs = qw + fr;

        // Q fragments (B-operand), pre-scaled at projection
        bf16x8 Qh[2], Ql[2];
#pragma unroll
        for (int dh = 0; dh < 2; ++dh) {
            size_t o = qkb + (size_t)(qw + fr) * DKH + fg * 8 + dh * 32;
            Qh[dh] = *(const bf16x8*)(g_qhi + o);
            Ql[dh] = *(const bf16x8*)(g_qlo + o);
        }

        float m_run = -1e30f, l_run = 0.f;
        f32x4 accO[4];
#pragma unroll
        for (int i = 0; i < 4; ++i) accO[i] = zv;

        const int nt = (q0 + 128) / 64;   // tiles of 64 kv
        for (int t = 0; t < nt; ++t) {
            const int kv0 = t * 64;
            __syncthreads();
            {   // stage: 1 chunk per array per thread, source pre-swizzled
                int ch = tid;                    // 0..511
                int r  = ch >> 3;                // row (kv for K, d for V)
                int c  = ch & 7;                 // 16B chunk in row
                int ck = c ^ (r & 7);
                size_t gk = qkb + (size_t)(kv0 + r) * DKH + ck * 8;
                size_t gv = vtb + (size_t)r * SEQ + kv0 + ck * 8;
                GLDS16(g_khi  + gk, (char*)sKh + ch * 16);
                GLDS16(g_klo  + gk, (char*)sKl + ch * 16);
                GLDS16(g_vthi + gv, (char*)sVh + ch * 16);
                GLDS16(g_vtlo + gv, (char*)sVl + ch * 16);
            }
            __syncthreads();

            if (kv0 > qw + 15) continue;   // wave-uniform: fully masked

            // ---- scores accS[kg]: D[kv][q], kv = kv0+16kg+4fg+r, q = fr
            f32x4 accS[4] = { zv, zv, zv, zv };
#pragma unroll
            for (int kg = 0; kg < 4; ++kg) {
                if (kv0 + kg*16 <= qw + 15) {
                    int rowb = (kg*16 + fr) * 128;
                    int fs = (fr & 7);
#pragma unroll
                    for (int dh = 0; dh < 2; ++dh) {
                        int cb = ((fg + 4*dh) ^ fs) * 16;
                        bf16x8 kh = *(const bf16x8*)((const char*)sKh + rowb + cb);
                        bf16x8 kl = *(const bf16x8*)((const char*)sKl + rowb + cb);
                        accS[kg] = MFMA16(kh, Qh[dh], accS[kg]);
                        accS[kg] = MFMA16(kh, Ql[dh], accS[kg]);
                        accS[kg] = MFMA16(kl, Qh[dh], accS[kg]);
                    }
                }
            }

            // ---- online softmax (scores already include 1/8*log2e)
            float p[16];
            float mt = -1e30f;
            if (kv0 + 63 <= qw) {          // wave-uniform: no masking needed
#pragma unroll
                for (int i = 0; i < 16; ++i) {
                    float s = accS[i >> 2][i & 3];
                    p[i] = s;
                    mt = fmaxf(mt, s);
                }
            } else {
#pragma unroll
                for (int kg = 0; kg < 4; ++kg)
#pragma unroll
                    for (int r = 0; r < 4; ++r) {
                        float s = accS[kg][r];
                        int kv = kv0 + kg*16 + fg*4 + r;
                        if (kv > qs) s = -1e30f;
                        p[kg*4 + r] = s;
                        mt = fmaxf(mt, s);
                    }
            }
            mt = fmaxf(mt, __shfl_xor(mt, 16));
            mt = fmaxf(mt, __shfl_xor(mt, 32));
            float mn   = fmaxf(m_run, mt);
            float corr = exp2f(m_run - mn);
            float rs = 0.f;
#pragma unroll
            for (int i = 0; i < 16; ++i) { p[i] = exp2f(p[i] - mn); rs += p[i]; }
            rs += __shfl_xor(rs, 16);
            rs += __shfl_xor(rs, 32);
            l_run = l_run * corr + rs;
            m_run = mn;

            float c4[4];
#pragma unroll
            for (int r = 0; r < 4; ++r) c4[r] = __shfl(corr, fg*4 + r);
#pragma unroll
            for (int ds = 0; ds < 4; ++ds)
#pragma unroll
                for (int r = 0; r < 4; ++r) accO[ds][r] *= c4[r];

            // ---- PV over two 32-kv halves
#pragma unroll
            for (int kh2 = 0; kh2 < 2; ++kh2) {
                if (kv0 + kh2*32 > qw + 15) break;   // wave-uniform
                bf16x8 ph, pl;
#pragma unroll
                for (int i = 0; i < 8; ++i) {
                    float pv = p[(2*kh2 + (i>>2))*4 + (i&3)];
                    ushort h = f2bf(pv);
                    ph[i] = (short)h;
                    pl[i] = (short)f2bf(pv - bf2f(h));
                }
#pragma unroll
                for (int ds = 0; ds < 4; ++ds) {
                    int d = ds*16 + fr;
                    int rowb = d * 128;
                    int fs = (fr & 7);
                    int c1 = (((4*kh2 +     (fg>>1)) ^ fs) << 4) + (fg & 1) * 8;
                    int c2 = (((4*kh2 + 2 + (fg>>1)) ^ fs) << 4) + (fg & 1) * 8;
                    union { bf16x8 v; uint2 u[2]; } Vhh, Vll;
                    Vhh.u[0] = *(const uint2*)((const char*)sVh + rowb + c1);
                    Vhh.u[1] = *(const uint2*)((const char*)sVh + rowb + c2);
                    Vll.u[0] = *(const uint2*)((const char*)sVl + rowb + c1);
                    Vll.u[1] = *(const uint2*)((const char*)sVl + rowb + c2);
                    accO[ds] = MFMA16(ph, Vhh.v, accO[ds]);
                    accO[ds] = MFMA16(ph, Vll.v, accO[ds]);
                    accO[ds] = MFMA16(pl, Vhh.v, accO[ds]);
                }
            }
        }

        // ---- epilogue for this q-block
        float l4[4];
#pragma unroll
        for (int r = 0; r < 4; ++r) l4[r] = 1.0f / __shfl(l_run, fg*4 + r);
#pragma unroll
        for (int ds = 0; ds < 4; ++ds)
#pragma unroll
            for (int r = 0; r < 4; ++r) {
                float v = accO[ds][r] * l4[r];
                int q   = qw + fg*4 + r;
                int tkn = (bh >> 4) * SEQ + q;
                int col = (bh & 15) * DKH + ds*16 + fr;
                size_t idx = (size_t)tkn * DMODEL + col;
                ushort hv = f2bf(v);
                g_aohi[idx] = hv;
                g_aolo[idx] = f2bf(v - bf2f(hv));
            }
        __syncthreads();   // don't let pass-1 staging race pass-0 LDS reads
    }
}

// ------------------------- launcher -------------------------
extern "C" void kernel_launch(void* const* d_in, const int* in_sizes, int n_in,
                              void* d_out, int out_size, void* d_ws, size_t ws_size,
                              hipStream_t stream) {
    const float* x  = (const float*)d_in[0];
    const float* wq = (const float*)d_in[1];
    const float* wk = (const float*)d_in[2];
    const float* wv = (const float*)d_in[3];
    const float* wo = (const float*)d_in[4];
    float* out = (float*)d_out;

    cvt_hilo<0><<<2048, 256, 0, stream>>>(x,  (NT*DMODEL)/4);
    cvt_hilo<1><<<512,  256, 0, stream>>>(wq, (DMODEL*DMODEL)/4);
    cvt_hilo<2><<<512,  256, 0, stream>>>(wk, (DMODEL*DMODEL)/4);
    cvt_hilo<3><<<512,  256, 0, stream>>>(wv, (DMODEL*DMODEL)/4);
    cvt_hilo<4><<<512,  256, 0, stream>>>(wo, (DMODEL*DMODEL)/4);

    const int NBLK = (DMODEL/128) * (NT/128);   // 512
    gemm_hilo<0><<<NBLK, 256, 0, stream>>>(out);
    gemm_hilo<1><<<NBLK, 256, 0, stream>>>(out);
    gemm_hilo<2><<<NBLK, 256, 0, stream>>>(out);

    attn_kernel<<<dim3(NQB/2, NBH), 512, 0, stream>>>();

    gemm_hilo<3><<<NBLK, 256, 0, stream>>>(out);
}

// Round 8
// 480.282 us; speedup vs baseline: 1.6668x; 1.0950x over previous
//
#include <hip/hip_runtime.h>
#include <hip/hip_bf16.h>

// ---------------------------------------------------------------------------
// MultiheadSelfAttention fp32 via hi/lo bf16 split (3-MFMA emulation).
// R8: fused QKV GEMM (1 dispatch, XCD-clustered m-panels), BK=64 K-loop
//     (half the barrier drains), attn defer-max + bh-XCD clustering.
// ---------------------------------------------------------------------------

#define DMODEL 1024
#define NH 16
#define DKH 64
#define NB 4
#define SEQ 2048
#define NT (NB*SEQ)   // 8192 tokens
#define NBH (NB*NH)   // 64
#define NQB (SEQ/128) // 16 q-blocks per bh

typedef __attribute__((ext_vector_type(8))) short bf16x8;
typedef __attribute__((ext_vector_type(4))) float f32x4;
typedef unsigned int u32;

#define MFMA16(a, b, c) __builtin_amdgcn_mfma_f32_16x16x32_bf16((a), (b), (c), 0, 0, 0)
#define GLDS16(gp, lp) \
    __builtin_amdgcn_global_load_lds((const __attribute__((address_space(1))) u32*)(const void*)(gp), \
                                     (__attribute__((address_space(3))) u32*)(void*)(lp), 16, 0, 0)

// ------------------------- device scratch -------------------------
__device__ ushort g_xhi[NT*DMODEL],  g_xlo[NT*DMODEL];
__device__ ushort g_wqhi[DMODEL*DMODEL], g_wqlo[DMODEL*DMODEL];
__device__ ushort g_wkhi[DMODEL*DMODEL], g_wklo[DMODEL*DMODEL];
__device__ ushort g_wvhi[DMODEL*DMODEL], g_wvlo[DMODEL*DMODEL];
__device__ ushort g_wohi[DMODEL*DMODEL], g_wolo[DMODEL*DMODEL];
__device__ ushort g_qhi[NBH*SEQ*DKH],  g_qlo[NBH*SEQ*DKH];    // pre-scaled by 1/8*log2e
__device__ ushort g_khi[NBH*SEQ*DKH],  g_klo[NBH*SEQ*DKH];
__device__ ushort g_vthi[NBH*DKH*SEQ], g_vtlo[NBH*DKH*SEQ];   // V^T: [bh][d][s]
__device__ ushort g_aohi[NT*DMODEL],   g_aolo[NT*DMODEL];

// ------------------------- helpers -------------------------
static __device__ __forceinline__ ushort f2bf(float f) {   // HW v_cvt, RNE
    union { __hip_bfloat16 b; ushort u; } cv;
    cv.b = __float2bfloat16(f);
    return cv.u;
}
static __device__ __forceinline__ float bf2f(ushort h) {
    return __uint_as_float(((unsigned)h) << 16);
}

// ------------------------- fp32 -> (hi,lo) bf16 -------------------------
template<int DST>
__global__ void cvt_hilo(const float* __restrict__ src, int n4) {
    ushort* hi; ushort* lo;
    if      (DST == 0) { hi = g_xhi;  lo = g_xlo;  }
    else if (DST == 1) { hi = g_wqhi; lo = g_wqlo; }
    else if (DST == 2) { hi = g_wkhi; lo = g_wklo; }
    else if (DST == 3) { hi = g_wvhi; lo = g_wvlo; }
    else               { hi = g_wohi; lo = g_wolo; }
    int stride = gridDim.x * blockDim.x;
    for (int i = blockIdx.x * blockDim.x + threadIdx.x; i < n4; i += stride) {
        float4 f = ((const float4*)src)[i];
        ushort4 h, l;
        h.x = f2bf(f.x); l.x = f2bf(f.x - bf2f(h.x));
        h.y = f2bf(f.y); l.y = f2bf(f.y - bf2f(h.y));
        h.z = f2bf(f.z); l.z = f2bf(f.z - bf2f(h.z));
        h.w = f2bf(f.w); l.w = f2bf(f.w - bf2f(h.w));
        ((ushort4*)hi)[i] = h;
        ((ushort4*)lo)[i] = l;
    }
}

// ------------------------- hi/lo GEMM, BK=64 -------------------------
// WHICH: 0 = fused QKV (grid 1536, B selected per n-panel), 3 = out proj.
// XCD remap: id&7 = XCD owns 8 consecutive m-panels (A-panel L2 locality).
// LDS [128 rows][8 chunks of 16B]; LDS chunk c holds global chunk c^(row&7)
// (pre-applied to global src); fragment reads apply the same XOR -> 2-way.
template<int WHICH>
__global__ __launch_bounds__(256) void gemm_hilo(float* __restrict__ outf) {
    __shared__ ushort sAh[128*64], sAl[128*64], sBh[128*64], sBl[128*64];  // 64 KB

    const int tid  = threadIdx.x;
    const int lane = tid & 63;
    const int wid  = tid >> 6;
    const int fr   = lane & 15;
    const int fg   = lane >> 4;

    int m0, n0g;
    if (WHICH == 0) {          // 1536 = 8 xcd * (24 n * 8 m)
        int id = blockIdx.x;
        int j  = id >> 3;
        int jn = j % 24, jm = j / 24;
        n0g = jn * 128;
        m0  = ((id & 7) * 8 + jm) * 128;
    } else {                   // 512 = 8 xcd * (8 n * 8 m)
        int id = blockIdx.x;
        int jj = id >> 3;
        n0g = (jj & 7) * 128;
        m0  = ((id & 7) * 8 + (jj >> 3)) * 128;
    }
    const int proj = (WHICH == 0) ? (n0g >> 10) : 3;   // 0=Q,1=K,2=V,3=AO
    const int nb0  = n0g & (DMODEL - 1);               // row base within weight

    const ushort* Ahi = (WHICH == 3) ? g_aohi : g_xhi;
    const ushort* Alo = (WHICH == 3) ? g_aolo : g_xlo;
    const ushort* Bhi = (WHICH == 3) ? g_wohi : (proj == 0) ? g_wqhi : (proj == 1) ? g_wkhi : g_wvhi;
    const ushort* Blo = (WHICH == 3) ? g_wolo : (proj == 0) ? g_wqlo : (proj == 1) ? g_wklo : g_wvlo;

    const int wm = (wid >> 1) * 64;
    const int wn = (wid & 1) * 64;

    f32x4 acc[4][4];
    const f32x4 zv = {0.f, 0.f, 0.f, 0.f};
#pragma unroll
    for (int i = 0; i < 4; ++i)
#pragma unroll
        for (int j = 0; j < 4; ++j) acc[i][j] = zv;

    for (int k0 = 0; k0 < DMODEL; k0 += 64) {
        __syncthreads();
#pragma unroll
        for (int i = 0; i < 4; ++i) {
            int ch  = tid + i * 256;          // 1024 chunks of 16B per buffer
            int row = ch >> 3;
            int c   = ch & 7;
            int cs  = c ^ (row & 7);          // pre-swizzled source chunk
            size_t ga = (size_t)(m0  + row) * DMODEL + k0 + cs * 8;
            size_t gb = (size_t)(nb0 + row) * DMODEL + k0 + cs * 8;
            GLDS16(Ahi + ga, (char*)sAh + ch * 16);
            GLDS16(Alo + ga, (char*)sAl + ch * 16);
            GLDS16(Bhi + gb, (char*)sBh + ch * 16);
            GLDS16(Blo + gb, (char*)sBl + ch * 16);
        }
        __syncthreads();

#pragma unroll
        for (int dh = 0; dh < 2; ++dh) {
            bf16x8 bh4[4], bl4[4];
#pragma unroll
            for (int nf = 0; nf < 4; ++nf) {
                int r   = wn + nf*16 + fr;
                int off = r * 128 + ((fg + 4*dh) ^ (r & 7)) * 16;   // bytes
                bh4[nf] = *(const bf16x8*)((const char*)sBh + off);
                bl4[nf] = *(const bf16x8*)((const char*)sBl + off);
            }
#pragma unroll
            for (int mf = 0; mf < 4; ++mf) {
                int r   = wm + mf*16 + fr;
                int off = r * 128 + ((fg + 4*dh) ^ (r & 7)) * 16;
                bf16x8 ah = *(const bf16x8*)((const char*)sAh + off);
                bf16x8 al = *(const bf16x8*)((const char*)sAl + off);
#pragma unroll
                for (int nf = 0; nf < 4; ++nf) {
                    acc[mf][nf] = MFMA16(ah, bh4[nf], acc[mf][nf]);
                    acc[mf][nf] = MFMA16(ah, bl4[nf], acc[mf][nf]);
                    acc[mf][nf] = MFMA16(al, bh4[nf], acc[mf][nf]);
                }
            }
        }
    }

    // C row = mf*16 + 4*fg + r (token), col = nf*16 + fr (channel)
#pragma unroll
    for (int mf = 0; mf < 4; ++mf)
#pragma unroll
        for (int nf = 0; nf < 4; ++nf) {
            if (WHICH == 0 && proj == 2) {
                // V^T: 4 consecutive s per reg -> one ushort4 store per array
                ushort4 hv4, lv4;
#pragma unroll
                for (int r = 0; r < 4; ++r) {
                    float v = acc[mf][nf][r];
                    ushort hv = f2bf(v);
                    ((ushort*)&hv4)[r] = hv;
                    ((ushort*)&lv4)[r] = f2bf(v - bf2f(hv));
                }
                int m = m0 + wm + mf*16 + fg*4;      // token of r=0 (mult of 4)
                int nl = nb0 + wn + nf*16 + fr;
                int b = m >> 11, s = m & (SEQ - 1);
                int h = nl >> 6, d = nl & 63;
                size_t idx = ((size_t)(b*NH + h) * DKH + d) * SEQ + s;
                *(ushort4*)(g_vthi + idx) = hv4;
                *(ushort4*)(g_vtlo + idx) = lv4;
            } else {
#pragma unroll
                for (int r = 0; r < 4; ++r) {
                    float v = acc[mf][nf][r];
                    if (WHICH == 0 && proj == 0) v *= 0.18033688011112042f; // 1/8*log2e
                    int m = m0 + wm + mf*16 + fg*4 + r;
                    if (WHICH == 3) {
                        int n = n0g + wn + nf*16 + fr;
                        outf[(size_t)m * DMODEL + n] = v;
                    } else {
                        int nl = nb0 + wn + nf*16 + fr;
                        int b = m >> 11, s = m & (SEQ - 1);
                        int h = nl >> 6, d = nl & 63;
                        ushort hv = f2bf(v);
                        ushort lv = f2bf(v - bf2f(hv));
                        size_t idx = ((size_t)(b*NH + h) * SEQ + s) * DKH + d;
                        if (proj == 0) { g_qhi[idx] = hv; g_qlo[idx] = lv; }
                        else           { g_khi[idx] = hv; g_klo[idx] = lv; }
                    }
                }
            }
        }
}

// ------------------------- flash attention (causal) -------------------------
// flat grid 512: bh = id&63 (so all 8 blocks of a bh share an XCD -> KV in
// that XCD's L2), qp = id>>6; block handles q-blocks {qp, 15-qp} -> constant
// 34 KV tiles per block. KV tile 64; K LDS [64 kv][64 d], V^T LDS [64 d][64 kv],
// linear dest via global_load_lds, 16B-chunk XOR (c^(row&7)) pre-applied to
// the GLOBAL source; reads apply the same XOR. Defer-max: skip O/l rescale
// when every lane's tile max is within 2^8 of its running max (T13).
__global__ __launch_bounds__(512, 4) void attn_kernel() {
    __shared__ ushort sKh[64*64], sKl[64*64], sVh[64*64], sVl[64*64];  // 32 KB

    const int tid  = threadIdx.x;
    const int lane = tid & 63;
    const int wid  = tid >> 6;          // 0..7
    const int fr   = lane & 15;
    const int fg   = lane >> 4;
    const int bh   = blockIdx.x & 63;
    const int qp   = blockIdx.x >> 6;
    const size_t qkb = (size_t)bh * SEQ * DKH;
    const size_t vtb = (size_t)bh * DKH * SEQ;
    const f32x4 zv = {0.f, 0.f, 0.f, 0.f};

    for (int pass = 0; pass < 2; ++pass) {
        const int qb = pass ? (NQB - 1 - qp) : qp;
        const int q0 = qb * 128;
        const int qw = q0 + wid * 16;
        const int qs = qw + fr;

        // Q fragments (B-operand), pre-scaled at projection
        bf16x8 Qh[2], Ql[2];
#pragma unroll
        for (int dh = 0; dh < 2; ++dh) {
            size_t o = qkb + (size_t)(qw + fr) * DKH + fg * 8 + dh * 32;
            Qh[dh] = *(const bf16x8*)(g_qhi + o);
            Ql[dh] = *(const bf16x8*)(g_qlo + o);
        }

        float m_run = -1e30f, l_run = 0.f;
        f32x4 accO[4];
#pragma unroll
        for (int i = 0; i < 4; ++i) accO[i] = zv;

        const int nt = (q0 + 128) / 64;   // tiles of 64 kv
        for (int t = 0; t < nt; ++t) {
            const int kv0 = t * 64;
            __syncthreads();
            {   // stage: 1 chunk per array per thread, source pre-swizzled
                int ch = tid;                    // 0..511
                int r  = ch >> 3;                // row (kv for K, d for V)
                int c  = ch & 7;                 // 16B chunk in row
                int ck = c ^ (r & 7);
                size_t gk = qkb + (size_t)(kv0 + r) * DKH + ck * 8;
                size_t gv = vtb + (size_t)r * SEQ + kv0 + ck * 8;
                GLDS16(g_khi  + gk, (char*)sKh + ch * 16);
                GLDS16(g_klo  + gk, (char*)sKl + ch * 16);
                GLDS16(g_vthi + gv, (char*)sVh + ch * 16);
                GLDS16(g_vtlo + gv, (char*)sVl + ch * 16);
            }
            __syncthreads();

            if (kv0 > qw + 15) continue;   // wave-uniform: fully masked

            // ---- scores accS[kg]: D[kv][q], kv = kv0+16kg+4fg+r, q = fr
            f32x4 accS[4] = { zv, zv, zv, zv };
#pragma unroll
            for (int kg = 0; kg < 4; ++kg) {
                if (kv0 + kg*16 <= qw + 15) {
                    int rowb = (kg*16 + fr) * 128;
                    int fs = (fr & 7);
#pragma unroll
                    for (int dh = 0; dh < 2; ++dh) {
                        int cb = ((fg + 4*dh) ^ fs) * 16;
                        bf16x8 kh = *(const bf16x8*)((const char*)sKh + rowb + cb);
                        bf16x8 kl = *(const bf16x8*)((const char*)sKl + rowb + cb);
                        accS[kg] = MFMA16(kh, Qh[dh], accS[kg]);
                        accS[kg] = MFMA16(kh, Ql[dh], accS[kg]);
                        accS[kg] = MFMA16(kl, Qh[dh], accS[kg]);
                    }
                }
            }

            // ---- online softmax (scores already include 1/8*log2e)
            float p[16];
            float mt = -1e30f;
            if (kv0 + 63 <= qw) {          // wave-uniform: no masking needed
#pragma unroll
                for (int i = 0; i < 16; ++i) {
                    float s = accS[i >> 2][i & 3];
                    p[i] = s;
                    mt = fmaxf(mt, s);
                }
            } else {
#pragma unroll
                for (int kg = 0; kg < 4; ++kg)
#pragma unroll
                    for (int r = 0; r < 4; ++r) {
                        float s = accS[kg][r];
                        int kv = kv0 + kg*16 + fg*4 + r;
                        if (kv > qs) s = -1e30f;
                        p[kg*4 + r] = s;
                        mt = fmaxf(mt, s);
                    }
            }
            mt = fmaxf(mt, __shfl_xor(mt, 16));
            mt = fmaxf(mt, __shfl_xor(mt, 32));

            // defer-max (T13): rescale only when some row grew past THR=8
            if (!__all(mt - m_run <= 8.0f)) {
                float mn   = fmaxf(m_run, mt);
                float corr = exp2f(m_run - mn);
                l_run *= corr;
                float c4[4];
#pragma unroll
                for (int r = 0; r < 4; ++r) c4[r] = __shfl(corr, fg*4 + r);
#pragma unroll
                for (int ds = 0; ds < 4; ++ds)
#pragma unroll
                    for (int r = 0; r < 4; ++r) accO[ds][r] *= c4[r];
                m_run = mn;
            }
            float rs = 0.f;
#pragma unroll
            for (int i = 0; i < 16; ++i) { p[i] = exp2f(p[i] - m_run); rs += p[i]; }
            rs += __shfl_xor(rs, 16);
            rs += __shfl_xor(rs, 32);
            l_run += rs;

            // ---- PV over two 32-kv halves
#pragma unroll
            for (int kh2 = 0; kh2 < 2; ++kh2) {
                if (kv0 + kh2*32 > qw + 15) break;   // wave-uniform
                bf16x8 ph, pl;
#pragma unroll
                for (int i = 0; i < 8; ++i) {
                    float pv = p[(2*kh2 + (i>>2))*4 + (i&3)];
                    ushort h = f2bf(pv);
                    ph[i] = (short)h;
                    pl[i] = (short)f2bf(pv - bf2f(h));
                }
#pragma unroll
                for (int ds = 0; ds < 4; ++ds) {
                    int d = ds*16 + fr;
                    int rowb = d * 128;
                    int fs = (fr & 7);
                    int c1 = (((4*kh2 +     (fg>>1)) ^ fs) << 4) + (fg & 1) * 8;
                    int c2 = (((4*kh2 + 2 + (fg>>1)) ^ fs) << 4) + (fg & 1) * 8;
                    union { bf16x8 v; uint2 u[2]; } Vhh, Vll;
                    Vhh.u[0] = *(const uint2*)((const char*)sVh + rowb + c1);
                    Vhh.u[1] = *(const uint2*)((const char*)sVh + rowb + c2);
                    Vll.u[0] = *(const uint2*)((const char*)sVl + rowb + c1);
                    Vll.u[1] = *(const uint2*)((const char*)sVl + rowb + c2);
                    accO[ds] = MFMA16(ph, Vhh.v, accO[ds]);
                    accO[ds] = MFMA16(ph, Vll.v, accO[ds]);
                    accO[ds] = MFMA16(pl, Vhh.v, accO[ds]);
                }
            }
        }

        // ---- epilogue for this q-block (register-only; no trailing barrier
        // needed: next pass's loop-top __syncthreads orders LDS reuse)
        float l4[4];
#pragma unroll
        for (int r = 0; r < 4; ++r) l4[r] = 1.0f / __shfl(l_run, fg*4 + r);
#pragma unroll
        for (int ds = 0; ds < 4; ++ds)
#pragma unroll
            for (int r = 0; r < 4; ++r) {
                float v = accO[ds][r] * l4[r];
                int q   = qw + fg*4 + r;
                int tkn = (bh >> 4) * SEQ + q;
                int col = (bh & 15) * DKH + ds*16 + fr;
                size_t idx = (size_t)tkn * DMODEL + col;
                ushort hv = f2bf(v);
                g_aohi[idx] = hv;
                g_aolo[idx] = f2bf(v - bf2f(hv));
            }
    }
}

// ------------------------- launcher -------------------------
extern "C" void kernel_launch(void* const* d_in, const int* in_sizes, int n_in,
                              void* d_out, int out_size, void* d_ws, size_t ws_size,
                              hipStream_t stream) {
    const float* x  = (const float*)d_in[0];
    const float* wq = (const float*)d_in[1];
    const float* wk = (const float*)d_in[2];
    const float* wv = (const float*)d_in[3];
    const float* wo = (const float*)d_in[4];
    float* out = (float*)d_out;

    cvt_hilo<0><<<2048, 256, 0, stream>>>(x,  (NT*DMODEL)/4);
    cvt_hilo<1><<<512,  256, 0, stream>>>(wq, (DMODEL*DMODEL)/4);
    cvt_hilo<2><<<512,  256, 0, stream>>>(wk, (DMODEL*DMODEL)/4);
    cvt_hilo<3><<<512,  256, 0, stream>>>(wv, (DMODEL*DMODEL)/4);
    cvt_hilo<4><<<512,  256, 0, stream>>>(wo, (DMODEL*DMODEL)/4);

    gemm_hilo<0><<<24 * 64, 256, 0, stream>>>(out);        // fused Q,K,V

    attn_kernel<<<(NQB/2) * NBH, 512, 0, stream>>>();

    gemm_hilo<3><<<8 * 64, 256, 0, stream>>>(out);         // output proj
}

// Round 10
// 356.764 us; speedup vs baseline: 2.2439x; 1.3462x over previous
//
#include <hip/hip_runtime.h>
#include <hip/hip_bf16.h>

// ---------------------------------------------------------------------------
// MultiheadSelfAttention fp32. Scores path (Q,K) in hi/lo bf16 3-MFMA
// emulation (2^-17); output-linear path (V, P·V, AO·Wo) in single fp16
// (2^-11) -- error budget ~1e-3 added, MFMA/staging on that path cut 3x.
// R10 = R9 resubmit (infra timeout; never benched).
// ---------------------------------------------------------------------------

#define DMODEL 1024
#define NH 16
#define DKH 64
#define NB 4
#define SEQ 2048
#define NT (NB*SEQ)   // 8192 tokens
#define NBH (NB*NH)   // 64
#define NQB (SEQ/128) // 16 q-blocks per bh

typedef __attribute__((ext_vector_type(8))) short bf16x8;
typedef __attribute__((ext_vector_type(8))) _Float16 f16x8;
typedef __attribute__((ext_vector_type(4))) float f32x4;
typedef unsigned int u32;

#define MFMA16(a, b, c)  __builtin_amdgcn_mfma_f32_16x16x32_bf16((a), (b), (c), 0, 0, 0)
#define MFMA16F(a, b, c) __builtin_amdgcn_mfma_f32_16x16x32_f16((a), (b), (c), 0, 0, 0)
#define GLDS16(gp, lp) \
    __builtin_amdgcn_global_load_lds((const __attribute__((address_space(1))) u32*)(const void*)(gp), \
                                     (__attribute__((address_space(3))) u32*)(void*)(lp), 16, 0, 0)

// ------------------------- device scratch -------------------------
__device__ ushort g_xhi[NT*DMODEL],  g_xlo[NT*DMODEL];        // bf16 hi/lo of x
__device__ ushort g_x16[NT*DMODEL];                           // fp16 x (V path)
__device__ ushort g_wqhi[DMODEL*DMODEL], g_wqlo[DMODEL*DMODEL];
__device__ ushort g_wkhi[DMODEL*DMODEL], g_wklo[DMODEL*DMODEL];
__device__ ushort g_wv16[DMODEL*DMODEL], g_wo16[DMODEL*DMODEL];  // fp16
__device__ ushort g_qhi[NBH*SEQ*DKH],  g_qlo[NBH*SEQ*DKH];    // pre-scaled by 1/8*log2e
__device__ ushort g_khi[NBH*SEQ*DKH],  g_klo[NBH*SEQ*DKH];
__device__ ushort g_vt16[NBH*DKH*SEQ];                        // V^T fp16: [bh][d][s]
__device__ ushort g_ao16[NT*DMODEL];                          // attn out fp16

// ------------------------- helpers -------------------------
static __device__ __forceinline__ ushort f2bf(float f) {   // HW v_cvt, RNE
    union { __hip_bfloat16 b; ushort u; } cv;
    cv.b = __float2bfloat16(f);
    return cv.u;
}
static __device__ __forceinline__ float bf2f(ushort h) {
    return __uint_as_float(((unsigned)h) << 16);
}
static __device__ __forceinline__ ushort f2h(float f) {    // HW v_cvt_f16_f32
    union { _Float16 h; ushort u; } cv;
    cv.h = (_Float16)f;
    return cv.u;
}

// ------------------------- fused input conversion -------------------------
// x -> (xhi, xlo bf16) + x16 fp16; Wq,Wk -> hi/lo bf16; Wv,Wo -> fp16.
__global__ void cvt_all(const float* __restrict__ x,  const float* __restrict__ wq,
                        const float* __restrict__ wk, const float* __restrict__ wv,
                        const float* __restrict__ wo) {
    const int NX = (NT*DMODEL)/4;       // 2097152 float4s
    const int NW = (DMODEL*DMODEL)/4;   // 262144
    const int total = NX + 4*NW;
    int stride = gridDim.x * blockDim.x;
    for (int i = blockIdx.x * blockDim.x + threadIdx.x; i < total; i += stride) {
        if (i < NX) {
            float4 f = ((const float4*)x)[i];
            ushort4 h, l, s;
            h.x = f2bf(f.x); l.x = f2bf(f.x - bf2f(h.x)); s.x = f2h(f.x);
            h.y = f2bf(f.y); l.y = f2bf(f.y - bf2f(h.y)); s.y = f2h(f.y);
            h.z = f2bf(f.z); l.z = f2bf(f.z - bf2f(h.z)); s.z = f2h(f.z);
            h.w = f2bf(f.w); l.w = f2bf(f.w - bf2f(h.w)); s.w = f2h(f.w);
            ((ushort4*)g_xhi)[i] = h;
            ((ushort4*)g_xlo)[i] = l;
            ((ushort4*)g_x16)[i] = s;
        } else if (i < NX + 2*NW) {
            int j = i - NX;
            const float* src = (j < NW) ? wq : wk;
            ushort* hi = (j < NW) ? g_wqhi : g_wkhi;
            ushort* lo = (j < NW) ? g_wqlo : g_wklo;
            int k = j & (NW - 1);
            float4 f = ((const float4*)src)[k];
            ushort4 h, l;
            h.x = f2bf(f.x); l.x = f2bf(f.x - bf2f(h.x));
            h.y = f2bf(f.y); l.y = f2bf(f.y - bf2f(h.y));
            h.z = f2bf(f.z); l.z = f2bf(f.z - bf2f(h.z));
            h.w = f2bf(f.w); l.w = f2bf(f.w - bf2f(h.w));
            ((ushort4*)hi)[k] = h;
            ((ushort4*)lo)[k] = l;
        } else {
            int j = i - NX - 2*NW;
            const float* src = (j < NW) ? wv : wo;
            ushort* ds = (j < NW) ? g_wv16 : g_wo16;
            int k = j & (NW - 1);
            float4 f = ((const float4*)src)[k];
            ushort4 s;
            s.x = f2h(f.x); s.y = f2h(f.y); s.z = f2h(f.z); s.w = f2h(f.w);
            ((ushort4*)ds)[k] = s;
        }
    }
}

// ------------------------- Q/K projection GEMM (bf16 hi/lo, BK=64) ----------
// grid 1024 = 8 xcd * (16 n-panels * 8 m-panels). proj = n0g>>10: 0=Q, 1=K.
// LDS [128 rows][8 chunks of 16B], chunk c holds global chunk c^(row&7).
__global__ __launch_bounds__(256) void gemm_qk() {
    __shared__ ushort sAh[128*64], sAl[128*64], sBh[128*64], sBl[128*64];  // 64 KB

    const int tid  = threadIdx.x;
    const int lane = tid & 63;
    const int wid  = tid >> 6;
    const int fr   = lane & 15;
    const int fg   = lane >> 4;

    const int id = blockIdx.x;
    const int j  = id >> 3;
    const int jn = j & 15, jm = j >> 4;
    const int n0g = jn * 128;                       // 0..2047
    const int m0  = ((id & 7) * 8 + jm) * 128;
    const int proj = n0g >> 10;                     // 0=Q, 1=K
    const int nb0  = n0g & (DMODEL - 1);

    const ushort* Bhi = proj ? g_wkhi : g_wqhi;
    const ushort* Blo = proj ? g_wklo : g_wqlo;

    const int wm = (wid >> 1) * 64;
    const int wn = (wid & 1) * 64;

    f32x4 acc[4][4];
    const f32x4 zv = {0.f, 0.f, 0.f, 0.f};
#pragma unroll
    for (int i = 0; i < 4; ++i)
#pragma unroll
        for (int jj = 0; jj < 4; ++jj) acc[i][jj] = zv;

    for (int k0 = 0; k0 < DMODEL; k0 += 64) {
        __syncthreads();
#pragma unroll
        for (int i = 0; i < 4; ++i) {
            int ch  = tid + i * 256;          // 1024 chunks of 16B per buffer
            int row = ch >> 3;
            int c   = ch & 7;
            int cs  = c ^ (row & 7);
            size_t ga = (size_t)(m0  + row) * DMODEL + k0 + cs * 8;
            size_t gb = (size_t)(nb0 + row) * DMODEL + k0 + cs * 8;
            GLDS16(g_xhi + ga, (char*)sAh + ch * 16);
            GLDS16(g_xlo + ga, (char*)sAl + ch * 16);
            GLDS16(Bhi   + gb, (char*)sBh + ch * 16);
            GLDS16(Blo   + gb, (char*)sBl + ch * 16);
        }
        __syncthreads();

#pragma unroll
        for (int dh = 0; dh < 2; ++dh) {
            bf16x8 bh4[4], bl4[4];
#pragma unroll
            for (int nf = 0; nf < 4; ++nf) {
                int r   = wn + nf*16 + fr;
                int off = r * 128 + ((fg + 4*dh) ^ (r & 7)) * 16;   // bytes
                bh4[nf] = *(const bf16x8*)((const char*)sBh + off);
                bl4[nf] = *(const bf16x8*)((const char*)sBl + off);
            }
#pragma unroll
            for (int mf = 0; mf < 4; ++mf) {
                int r   = wm + mf*16 + fr;
                int off = r * 128 + ((fg + 4*dh) ^ (r & 7)) * 16;
                bf16x8 ah = *(const bf16x8*)((const char*)sAh + off);
                bf16x8 al = *(const bf16x8*)((const char*)sAl + off);
#pragma unroll
                for (int nf = 0; nf < 4; ++nf) {
                    acc[mf][nf] = MFMA16(ah, bh4[nf], acc[mf][nf]);
                    acc[mf][nf] = MFMA16(ah, bl4[nf], acc[mf][nf]);
                    acc[mf][nf] = MFMA16(al, bh4[nf], acc[mf][nf]);
                }
            }
        }
    }

    // C row = mf*16 + 4*fg + r (token), col = nf*16 + fr (channel)
#pragma unroll
    for (int mf = 0; mf < 4; ++mf)
#pragma unroll
        for (int nf = 0; nf < 4; ++nf)
#pragma unroll
            for (int r = 0; r < 4; ++r) {
                float v = acc[mf][nf][r];
                if (proj == 0) v *= 0.18033688011112042f;   // 1/8 * log2(e)
                int m  = m0 + wm + mf*16 + fg*4 + r;
                int nl = nb0 + wn + nf*16 + fr;
                int b = m >> 11, s = m & (SEQ - 1);
                int h = nl >> 6, d = nl & 63;
                ushort hv = f2bf(v);
                ushort lv = f2bf(v - bf2f(hv));
                size_t idx = ((size_t)(b*NH + h) * SEQ + s) * DKH + d;
                if (proj == 0) { g_qhi[idx] = hv; g_qlo[idx] = lv; }
                else           { g_khi[idx] = hv; g_klo[idx] = lv; }
            }
}

// ------------------------- fp16 single-stream GEMM (BK=64) ------------------
// WHICH=2: V proj (A=x16, B=Wv16, out V^T fp16). WHICH=3: AO proj
// (A=ao16, B=Wo16, out fp32 d_out). grid 512 = 8 xcd * (8 n * 8 m). 32 KB LDS.
template<int WHICH>
__global__ __launch_bounds__(256) void gemm_f16(float* __restrict__ outf) {
    __shared__ ushort sA[128*64], sB[128*64];   // 32 KB

    const int tid  = threadIdx.x;
    const int lane = tid & 63;
    const int wid  = tid >> 6;
    const int fr   = lane & 15;
    const int fg   = lane >> 4;

    const int id = blockIdx.x;
    const int jj = id >> 3;
    const int n0 = (jj & 7) * 128;
    const int m0 = ((id & 7) * 8 + (jj >> 3)) * 128;

    const ushort* A = (WHICH == 2) ? g_x16  : g_ao16;
    const ushort* B = (WHICH == 2) ? g_wv16 : g_wo16;

    const int wm = (wid >> 1) * 64;
    const int wn = (wid & 1) * 64;

    f32x4 acc[4][4];
    const f32x4 zv = {0.f, 0.f, 0.f, 0.f};
#pragma unroll
    for (int i = 0; i < 4; ++i)
#pragma unroll
        for (int j = 0; j < 4; ++j) acc[i][j] = zv;

    for (int k0 = 0; k0 < DMODEL; k0 += 64) {
        __syncthreads();
#pragma unroll
        for (int i = 0; i < 4; ++i) {
            int ch  = tid + i * 256;          // 1024 chunks per buffer
            int row = ch >> 3;
            int c   = ch & 7;
            int cs  = c ^ (row & 7);
            size_t ga = (size_t)(m0 + row) * DMODEL + k0 + cs * 8;
            size_t gb = (size_t)(n0 + row) * DMODEL + k0 + cs * 8;
            GLDS16(A + ga, (char*)sA + ch * 16);
            GLDS16(B + gb, (char*)sB + ch * 16);
        }
        __syncthreads();

#pragma unroll
        for (int dh = 0; dh < 2; ++dh) {
            f16x8 b4[4];
#pragma unroll
            for (int nf = 0; nf < 4; ++nf) {
                int r   = wn + nf*16 + fr;
                int off = r * 128 + ((fg + 4*dh) ^ (r & 7)) * 16;
                b4[nf] = *(const f16x8*)((const char*)sB + off);
            }
#pragma unroll
            for (int mf = 0; mf < 4; ++mf) {
                int r   = wm + mf*16 + fr;
                int off = r * 128 + ((fg + 4*dh) ^ (r & 7)) * 16;
                f16x8 a = *(const f16x8*)((const char*)sA + off);
#pragma unroll
                for (int nf = 0; nf < 4; ++nf)
                    acc[mf][nf] = MFMA16F(a, b4[nf], acc[mf][nf]);
            }
        }
    }

#pragma unroll
    for (int mf = 0; mf < 4; ++mf)
#pragma unroll
        for (int nf = 0; nf < 4; ++nf) {
            if (WHICH == 2) {
                // V^T fp16: 4 consecutive s per acc reg -> one ushort4 store
                ushort4 s4;
#pragma unroll
                for (int r = 0; r < 4; ++r) ((ushort*)&s4)[r] = f2h(acc[mf][nf][r]);
                int m  = m0 + wm + mf*16 + fg*4;     // token of r=0 (mult of 4)
                int nl = n0 + wn + nf*16 + fr;
                int b = m >> 11, s = m & (SEQ - 1);
                int h = nl >> 6, d = nl & 63;
                size_t idx = ((size_t)(b*NH + h) * DKH + d) * SEQ + s;
                *(ushort4*)(g_vt16 + idx) = s4;
            } else {
#pragma unroll
                for (int r = 0; r < 4; ++r) {
                    int m = m0 + wm + mf*16 + fg*4 + r;
                    int n = n0 + wn + nf*16 + fr;
                    outf[(size_t)m * DMODEL + n] = acc[mf][nf][r];
                }
            }
        }
}

// ------------------------- flash attention (causal) -------------------------
// flat grid 512: bh = id&63 (8 blocks of a bh share an XCD), qp = id>>6;
// block handles q-blocks {qp, 15-qp} -> constant 34 KV tiles. KV tile 64.
// K hi/lo bf16 in LDS; V^T single fp16. 16B-chunk XOR (c^(row&7)) pre-applied
// to global src; reads apply the same XOR. Defer-max THR=8 (log2 units).
__global__ __launch_bounds__(512, 4) void attn_kernel() {
    __shared__ ushort sKh[64*64], sKl[64*64], sV16[64*64];   // 24 KB

    const int tid  = threadIdx.x;
    const int lane = tid & 63;
    const int wid  = tid >> 6;          // 0..7
    const int fr   = lane & 15;
    const int fg   = lane >> 4;
    const int bh   = blockIdx.x & 63;
    const int qp   = blockIdx.x >> 6;
    const size_t qkb = (size_t)bh * SEQ * DKH;
    const size_t vtb = (size_t)bh * DKH * SEQ;
    const f32x4 zv = {0.f, 0.f, 0.f, 0.f};

    for (int pass = 0; pass < 2; ++pass) {
        const int qb = pass ? (NQB - 1 - qp) : qp;
        const int q0 = qb * 128;
        const int qw = q0 + wid * 16;
        const int qs = qw + fr;

        // Q fragments (B-operand), pre-scaled at projection
        bf16x8 Qh[2], Ql[2];
#pragma unroll
        for (int dh = 0; dh < 2; ++dh) {
            size_t o = qkb + (size_t)(qw + fr) * DKH + fg * 8 + dh * 32;
            Qh[dh] = *(const bf16x8*)(g_qhi + o);
            Ql[dh] = *(const bf16x8*)(g_qlo + o);
        }

        float m_run = -1e30f, l_run = 0.f;
        f32x4 accO[4];
#pragma unroll
        for (int i = 0; i < 4; ++i) accO[i] = zv;

        const int nt = (q0 + 128) / 64;   // tiles of 64 kv
        for (int t = 0; t < nt; ++t) {
            const int kv0 = t * 64;
            __syncthreads();
            {   // stage: 1 chunk per array per thread, source pre-swizzled
                int ch = tid;                    // 0..511
                int r  = ch >> 3;                // row (kv for K, d for V)
                int c  = ch & 7;                 // 16B chunk in row
                int ck = c ^ (r & 7);
                size_t gk = qkb + (size_t)(kv0 + r) * DKH + ck * 8;
                size_t gv = vtb + (size_t)r * SEQ + kv0 + ck * 8;
                GLDS16(g_khi  + gk, (char*)sKh + ch * 16);
                GLDS16(g_klo  + gk, (char*)sKl + ch * 16);
                GLDS16(g_vt16 + gv, (char*)sV16 + ch * 16);
            }
            __syncthreads();

            if (kv0 > qw + 15) continue;   // wave-uniform: fully masked

            // ---- scores accS[kg]: D[kv][q], kv = kv0+16kg+4fg+r, q = fr
            f32x4 accS[4] = { zv, zv, zv, zv };
#pragma unroll
            for (int kg = 0; kg < 4; ++kg) {
                if (kv0 + kg*16 <= qw + 15) {
                    int rowb = (kg*16 + fr) * 128;
                    int fs = (fr & 7);
#pragma unroll
                    for (int dh = 0; dh < 2; ++dh) {
                        int cb = ((fg + 4*dh) ^ fs) * 16;
                        bf16x8 kh = *(const bf16x8*)((const char*)sKh + rowb + cb);
                        bf16x8 kl = *(const bf16x8*)((const char*)sKl + rowb + cb);
                        accS[kg] = MFMA16(kh, Qh[dh], accS[kg]);
                        accS[kg] = MFMA16(kh, Ql[dh], accS[kg]);
                        accS[kg] = MFMA16(kl, Qh[dh], accS[kg]);
                    }
                }
            }

            // ---- online softmax (scores already include 1/8*log2e)
            float p[16];
            float mt = -1e30f;
            if (kv0 + 63 <= qw) {          // wave-uniform: no masking needed
#pragma unroll
                for (int i = 0; i < 16; ++i) {
                    float s = accS[i >> 2][i & 3];
                    p[i] = s;
                    mt = fmaxf(mt, s);
                }
            } else {
#pragma unroll
                for (int kg = 0; kg < 4; ++kg)
#pragma unroll
                    for (int r = 0; r < 4; ++r) {
                        float s = accS[kg][r];
                        int kv = kv0 + kg*16 + fg*4 + r;
                        if (kv > qs) s = -1e30f;
                        p[kg*4 + r] = s;
                        mt = fmaxf(mt, s);
                    }
            }
            mt = fmaxf(mt, __shfl_xor(mt, 16));
            mt = fmaxf(mt, __shfl_xor(mt, 32));

            // defer-max (T13): rescale only when some row grew past THR=8
            if (!__all(mt - m_run <= 8.0f)) {
                float mn   = fmaxf(m_run, mt);
                float corr = exp2f(m_run - mn);
                l_run *= corr;
                float c4[4];
#pragma unroll
                for (int r = 0; r < 4; ++r) c4[r] = __shfl(corr, fg*4 + r);
#pragma unroll
                for (int ds = 0; ds < 4; ++ds)
#pragma unroll
                    for (int r = 0; r < 4; ++r) accO[ds][r] *= c4[r];
                m_run = mn;
            }
            float rs = 0.f;
#pragma unroll
            for (int i = 0; i < 16; ++i) { p[i] = exp2f(p[i] - m_run); rs += p[i]; }
            rs += __shfl_xor(rs, 16);
            rs += __shfl_xor(rs, 32);
            l_run += rs;

            // ---- PV (fp16 single stream) over two 32-kv halves
#pragma unroll
            for (int kh2 = 0; kh2 < 2; ++kh2) {
                if (kv0 + kh2*32 > qw + 15) break;   // wave-uniform
                union { f16x8 v; ushort u[8]; } p16;
#pragma unroll
                for (int i = 0; i < 8; ++i)
                    p16.u[i] = f2h(p[(2*kh2 + (i>>2))*4 + (i&3)]);
#pragma unroll
                for (int ds = 0; ds < 4; ++ds) {
                    int d = ds*16 + fr;
                    int rowb = d * 128;
                    int fs = (fr & 7);
                    int c1 = (((4*kh2 +     (fg>>1)) ^ fs) << 4) + (fg & 1) * 8;
                    int c2 = (((4*kh2 + 2 + (fg>>1)) ^ fs) << 4) + (fg & 1) * 8;
                    union { f16x8 v; uint2 u[2]; } V16;
                    V16.u[0] = *(const uint2*)((const char*)sV16 + rowb + c1);
                    V16.u[1] = *(const uint2*)((const char*)sV16 + rowb + c2);
                    accO[ds] = MFMA16F(p16.v, V16.v, accO[ds]);
                }
            }
        }

        // ---- epilogue for this q-block (register-only)
        float l4[4];
#pragma unroll
        for (int r = 0; r < 4; ++r) l4[r] = 1.0f / __shfl(l_run, fg*4 + r);
#pragma unroll
        for (int ds = 0; ds < 4; ++ds)
#pragma unroll
            for (int r = 0; r < 4; ++r) {
                float v = accO[ds][r] * l4[r];
                int q   = qw + fg*4 + r;
                int tkn = (bh >> 4) * SEQ + q;
                int col = (bh & 15) * DKH + ds*16 + fr;
                g_ao16[(size_t)tkn * DMODEL + col] = f2h(v);
            }
    }
}

// ------------------------- launcher -------------------------
extern "C" void kernel_launch(void* const* d_in, const int* in_sizes, int n_in,
                              void* d_out, int out_size, void* d_ws, size_t ws_size,
                              hipStream_t stream) {
    const float* x  = (const float*)d_in[0];
    const float* wq = (const float*)d_in[1];
    const float* wk = (const float*)d_in[2];
    const float* wv = (const float*)d_in[3];
    const float* wo = (const float*)d_in[4];
    float* out = (float*)d_out;

    cvt_all<<<2048, 256, 0, stream>>>(x, wq, wk, wv, wo);

    gemm_qk<<<1024, 256, 0, stream>>>();          // Q and K projections
    gemm_f16<2><<<512, 256, 0, stream>>>(out);    // V projection -> V^T fp16

    attn_kernel<<<(NQB/2) * NBH, 512, 0, stream>>>();

    gemm_f16<3><<<512, 256, 0, stream>>>(out);    // output projection
}